// Round 1
// baseline (4206.829 us; speedup 1.0000x reference)
//
#include <hip/hip_runtime.h>
#include <hip/hip_bf16.h>
#include <math.h>

#define Bsz 8
#define Lq  512
#define INF_ 64
#define Dm  512
#define Hh  8
#define El  4
#define DF  2048
#define HD  64   // head dim
#define NEG (-3.0e38f)

// ---------------- workspace layout (floats) ----------------
#define OFF_H    0L
#define OFF_HPAD 2097152L
#define OFF_TMP  4202496L
#define OFF_Q    6299648L
#define OFF_K    8396800L
#define OFF_V    10493952L
#define OFF_AO   12591104L
#define OFF_MID  14688256L
#define OFF_SC   23076864L
#define OFF_WC   39854080L
#define WS_FLOATS 40640512L

// ---------------- input embedding ----------------
__global__ __launch_bounds__(256) void embed_kernel(
    const float* __restrict__ x, const float* __restrict__ tf,
    const float* __restrict__ in_w, const float* __restrict__ in_b,
    const float* __restrict__ pos_emb, const float* __restrict__ temp_w,
    const float* __restrict__ temp_b, const float* __restrict__ pos_scale,
    const float* __restrict__ temp_scale, float* __restrict__ h)
{
    int bl = blockIdx.x;           // b*512 + l
    int l  = bl & 511;
    __shared__ float xs[64];
    __shared__ float tfs[2];
    int tid = threadIdx.x;
    if (tid < 64) xs[tid] = x[(long)bl * 64 + tid];
    if (tid < 2)  tfs[tid] = tf[(long)bl * 2 + tid];
    __syncthreads();
    float ps = pos_scale[0], ts = temp_scale[0];
    for (int d = tid; d < Dm; d += 256) {
        float acc = in_b[d];
#pragma unroll
        for (int k2 = 0; k2 < 64; k2++) acc += xs[k2] * in_w[k2 * Dm + d];
        acc += ps * pos_emb[(long)l * Dm + d];
        acc += ts * (tfs[0] * temp_w[d] + tfs[1] * temp_w[Dm + d] + temp_b[d]);
        h[(long)bl * Dm + d] = acc;
    }
}

// ---------------- left-pad h by 2 along time ----------------
__global__ __launch_bounds__(256) void pad_kernel(const float* __restrict__ h, float* __restrict__ hpad)
{
    long i = (long)blockIdx.x * 256 + threadIdx.x;
    const long total = (long)Bsz * (Lq + 2) * Dm;
    if (i >= total) return;
    int d = (int)(i & 511);
    long rest = i >> 9;
    int t = (int)(rest % (Lq + 2));
    int b = (int)(rest / (Lq + 2));
    hpad[i] = (t < 2) ? 0.f : h[((long)b * Lq + (t - 2)) * Dm + d];
}

// ---------------- conv weight transform: [dout][din][kk] -> [kk][din][dout] ----------------
__global__ __launch_bounds__(256) void convw_kernel(const float* __restrict__ cw, float* __restrict__ wc)
{
    long i = (long)blockIdx.x * 256 + threadIdx.x;
    const long total = 3L * Dm * Dm;
    if (i >= total) return;
    int dout = (int)(i & 511);
    int din  = (int)((i >> 9) & 511);
    int kk   = (int)(i >> 18);
    wc[i] = cw[(long)dout * (Dm * 3) + din * 3 + kk];
}

// ---------------- generic tiled f32 GEMM: C = A@B (+bias)(+relu)(+residual) ----------------
__global__ __launch_bounds__(256) void gemm_nn(
    const float* __restrict__ A, int lda, long sAz,
    const float* __restrict__ B, int ldb, long sBz,
    float* __restrict__ C, int ldc, long sCz,
    int M, int N, int K,
    const float* __restrict__ bias,
    const float* __restrict__ R, int doRelu)
{
    int z = blockIdx.z;
    A += (long)z * sAz; B += (long)z * sBz; C += (long)z * sCz;
    const float* Rz = R ? R + (long)z * sCz : nullptr;
    int n0 = blockIdx.x * 64, m0 = blockIdx.y * 64;
    int tid = threadIdx.x;
    int tx = tid & 15, ty = tid >> 4;
    __shared__ float As[16][65];
    __shared__ float Bs[16][65];
    float acc[4][4] = {};
    int am = tid >> 4;   // 0..15
    int ak = tid & 15;   // 0..15
    int bk = tid >> 6;   // 0..3
    int bn = tid & 63;   // 0..63
    for (int k0 = 0; k0 < K; k0 += 16) {
#pragma unroll
        for (int i = 0; i < 4; i++)
            As[ak][am + 16 * i] = A[(long)(m0 + am + 16 * i) * lda + k0 + ak];
#pragma unroll
        for (int i = 0; i < 4; i++)
            Bs[bk + 4 * i][bn] = B[(long)(k0 + bk + 4 * i) * ldb + n0 + bn];
        __syncthreads();
#pragma unroll
        for (int kk = 0; kk < 16; kk++) {
            float a[4], b[4];
#pragma unroll
            for (int i = 0; i < 4; i++) a[i] = As[kk][ty * 4 + i];
#pragma unroll
            for (int j = 0; j < 4; j++) b[j] = Bs[kk][tx * 4 + j];
#pragma unroll
            for (int i = 0; i < 4; i++)
#pragma unroll
                for (int j = 0; j < 4; j++) acc[i][j] += a[i] * b[j];
        }
        __syncthreads();
    }
#pragma unroll
    for (int i = 0; i < 4; i++) {
        int m = m0 + ty * 4 + i;
#pragma unroll
        for (int j = 0; j < 4; j++) {
            int n = n0 + tx * 4 + j;
            float c = acc[i][j];
            if (bias) c += bias[n];
            if (doRelu) c = fmaxf(c, 0.f);
            if (Rz) c += Rz[(long)m * ldc + n];
            C[(long)m * ldc + n] = c;
        }
    }
}

// ---------------- residual + LayerNorm (in place into h) ----------------
__global__ __launch_bounds__(256) void ln_kernel(
    float* __restrict__ h, const float* __restrict__ r,
    const float* __restrict__ sc, const float* __restrict__ bi)
{
    long base = (long)blockIdx.x * Dm;
    int tid = threadIdx.x;
    float v0 = h[base + tid] + r[base + tid];
    float v1 = h[base + tid + 256] + r[base + tid + 256];
    __shared__ float red[8];
    int lane = tid & 63, wid = tid >> 6;
    float s = v0 + v1;
    for (int off = 32; off; off >>= 1) s += __shfl_down(s, off);
    if (!lane) red[wid] = s;
    __syncthreads();
    float mean = (red[0] + red[1] + red[2] + red[3]) * (1.f / 512.f);
    float d0 = v0 - mean, d1 = v1 - mean;
    float vs = d0 * d0 + d1 * d1;
    for (int off = 32; off; off >>= 1) vs += __shfl_down(vs, off);
    if (!lane) red[4 + wid] = vs;
    __syncthreads();
    float var = (red[4] + red[5] + red[6] + red[7]) * (1.f / 512.f);
    float inv = rsqrtf(var + 1e-5f);
    h[base + tid]       = d0 * inv * sc[tid] + bi[tid];
    h[base + tid + 256] = d1 * inv * sc[tid + 256] + bi[tid + 256];
}

// ---------------- scores = scale * q @ k^T (per b,h), lower-triangle tiles only ----------------
__global__ __launch_bounds__(256) void scores_kernel(
    const float* __restrict__ q, const float* __restrict__ k, float* __restrict__ sc)
{
    if (blockIdx.x > blockIdx.y) return;   // tile fully above diagonal -> never read
    int z = blockIdx.z;
    int b = z >> 3, hh = z & 7;
    int i0 = blockIdx.y * 64, j0 = blockIdx.x * 64;
    const float* qp = q + (long)b * (Lq * Dm) + hh * HD;
    const float* kp = k + (long)b * (Lq * Dm) + hh * HD;
    __shared__ float Qs[64][65];
    __shared__ float Ks[64][65];
    int tid = threadIdx.x;
    int c = tid & 63, r4 = tid >> 6;
#pragma unroll
    for (int i = 0; i < 16; i++) {
        int r = r4 + i * 4;
        Qs[r][c] = qp[(long)(i0 + r) * Dm + c];
        Ks[r][c] = kp[(long)(j0 + r) * Dm + c];
    }
    __syncthreads();
    int tx = tid & 15, ty = tid >> 4;
    float acc[4][4] = {};
#pragma unroll 8
    for (int kk = 0; kk < 64; kk++) {
        float a[4], b4[4];
#pragma unroll
        for (int i = 0; i < 4; i++) a[i] = Qs[ty * 4 + i][kk];
#pragma unroll
        for (int j = 0; j < 4; j++) b4[j] = Ks[tx * 4 + j][kk];
#pragma unroll
        for (int i = 0; i < 4; i++)
#pragma unroll
            for (int j = 0; j < 4; j++) acc[i][j] += a[i] * b4[j];
    }
    float* outp = sc + (long)z * (Lq * Lq);
#pragma unroll
    for (int i = 0; i < 4; i++)
#pragma unroll
        for (int j = 0; j < 4; j++)
            outp[(long)(i0 + ty * 4 + i) * Lq + j0 + tx * 4 + j] = acc[i][j] * 0.125f;
}

// ---------------- per-row top-k(256) threshold + softmax (in place) ----------------
__global__ __launch_bounds__(256) void topk_softmax(float* __restrict__ sc)
{
    int row = blockIdx.x;              // z*512 + q
    int q = row & 511;
    int z = row >> 9;
    float* s = sc + (long)z * (Lq * Lq) + (long)q * Lq;
    __shared__ float srt[512];
    __shared__ float red[16];
    int tid = threadIdx.x;
    int j1 = tid + 256;
    float v0 = (tid <= q) ? s[tid] : NEG;
    float v1 = (j1 <= q) ? s[j1] : NEG;
    float T = NEG;
    if (q >= 256) {                    // need 256th largest among q+1 >= 257 valid
        srt[tid] = v0; srt[j1] = v1;
        for (int ksz = 2; ksz <= 512; ksz <<= 1) {
            for (int jj = ksz >> 1; jj > 0; jj >>= 1) {
                __syncthreads();
                int i = ((tid & ~(jj - 1)) << 1) | (tid & (jj - 1));
                int p = i | jj;
                float a = srt[i], b = srt[p];
                bool asc = ((i & ksz) == 0);
                if ((a > b) == asc) { srt[i] = b; srt[p] = a; }
            }
        }
        __syncthreads();
        T = srt[256];                  // ascending: 256th largest
    }
    // max over valid entries (max is always kept)
    int lane = tid & 63, wid = tid >> 6;
    float m = fmaxf(v0, v1);
    for (int off = 32; off; off >>= 1) m = fmaxf(m, __shfl_down(m, off));
    if (!lane) red[wid] = m;
    __syncthreads();
    m = fmaxf(fmaxf(red[0], red[1]), fmaxf(red[2], red[3]));
    bool k0 = (tid <= q) && (v0 >= T);
    bool k1 = (j1 <= q) && (v1 >= T);
    float e0 = k0 ? expf(v0 - m) : 0.f;
    float e1 = k1 ? expf(v1 - m) : 0.f;
    float ssum = e0 + e1;
    for (int off = 32; off; off >>= 1) ssum += __shfl_down(ssum, off);
    if (!lane) red[8 + wid] = ssum;
    __syncthreads();
    float inv = 1.f / (red[8] + red[9] + red[10] + red[11]);
    s[tid] = e0 * inv;
    s[j1]  = e1 * inv;
}

// ---------------- attnout[b,q,h*64+d] = sum_k attn[z,q,k] * v[b,k,h*64+d] ----------------
__global__ __launch_bounds__(256) void attnv_kernel(
    const float* __restrict__ attn, const float* __restrict__ v, float* __restrict__ ao)
{
    int z = blockIdx.z;
    int b = z >> 3, hh = z & 7;
    int m0 = blockIdx.y * 64;
    const float* Az = attn + (long)z * (Lq * Lq);
    const float* Bz = v + (long)b * (Lq * Dm) + hh * HD;
    float* Cz = ao + (long)b * (Lq * Dm) + hh * HD;
    __shared__ float As[16][65];
    __shared__ float Bs[16][65];
    int tid = threadIdx.x;
    int am = tid >> 4, ak = tid & 15;
    int bk = tid >> 6, bn = tid & 63;
    int tx = tid & 15, ty = tid >> 4;
    float acc[4][4] = {};
    int Klim = m0 + 64;                // causal: attn[q][k]=0 for k>q
    for (int k0 = 0; k0 < Klim; k0 += 16) {
#pragma unroll
        for (int i = 0; i < 4; i++)
            As[ak][am + 16 * i] = Az[(long)(m0 + am + 16 * i) * Lq + k0 + ak];
#pragma unroll
        for (int i = 0; i < 4; i++)
            Bs[bk + 4 * i][bn] = Bz[(long)(k0 + bk + 4 * i) * Dm + bn];
        __syncthreads();
#pragma unroll
        for (int kk = 0; kk < 16; kk++) {
            float a[4], b4[4];
#pragma unroll
            for (int i = 0; i < 4; i++) a[i] = As[kk][ty * 4 + i];
#pragma unroll
            for (int j = 0; j < 4; j++) b4[j] = Bs[kk][tx * 4 + j];
#pragma unroll
            for (int i = 0; i < 4; i++)
#pragma unroll
                for (int j = 0; j < 4; j++) acc[i][j] += a[i] * b4[j];
        }
        __syncthreads();
    }
#pragma unroll
    for (int i = 0; i < 4; i++)
#pragma unroll
        for (int j = 0; j < 4; j++)
            Cz[(long)(m0 + ty * 4 + i) * Dm + tx * 4 + j] = acc[i][j];
}

extern "C" void kernel_launch(void* const* d_in, const int* in_sizes, int n_in,
                              void* d_out, int out_size, void* d_ws, size_t ws_size,
                              hipStream_t stream)
{
    const float* x        = (const float*)d_in[0];
    const float* tf       = (const float*)d_in[1];
    const float* in_w     = (const float*)d_in[2];
    const float* in_b     = (const float*)d_in[3];
    const float* pos_emb  = (const float*)d_in[4];
    const float* temp_w   = (const float*)d_in[5];
    const float* temp_b   = (const float*)d_in[6];
    const float* pos_scale= (const float*)d_in[7];
    const float* temp_scale=(const float*)d_in[8];
    const float* conv_w   = (const float*)d_in[9];
    const float* conv_b   = (const float*)d_in[10];
    const float* qw       = (const float*)d_in[11];
    const float* qb       = (const float*)d_in[12];
    const float* kw       = (const float*)d_in[13];
    const float* kb       = (const float*)d_in[14];
    const float* vw       = (const float*)d_in[15];
    const float* vb       = (const float*)d_in[16];
    const float* ow       = (const float*)d_in[17];
    const float* ob       = (const float*)d_in[18];
    const float* f1w      = (const float*)d_in[19];
    const float* f1b      = (const float*)d_in[20];
    const float* f2w      = (const float*)d_in[21];
    const float* f2b      = (const float*)d_in[22];
    const float* n1s      = (const float*)d_in[23];
    const float* n1b      = (const float*)d_in[24];
    const float* n2s      = (const float*)d_in[25];
    const float* n2b      = (const float*)d_in[26];

    if (ws_size < WS_FLOATS * sizeof(float)) return;   // workspace too small -> visible failure

    float* ws   = (float*)d_ws;
    float* h    = ws + OFF_H;
    float* hpad = ws + OFF_HPAD;
    float* tmp  = ws + OFF_TMP;
    float* qv   = ws + OFF_Q;
    float* kv   = ws + OFF_K;
    float* vv   = ws + OFF_V;
    float* ao   = ws + OFF_AO;
    float* mid  = ws + OFF_MID;
    float* scb  = ws + OFF_SC;
    float* wc   = ws + OFF_WC;

    embed_kernel<<<Bsz * Lq, 256, 0, stream>>>(x, tf, in_w, in_b, pos_emb, temp_w, temp_b,
                                               pos_scale, temp_scale, h);

    for (int l = 0; l < El; l++) {
        // conv
        pad_kernel<<<(Bsz * (Lq + 2) * Dm + 255) / 256, 256, 0, stream>>>(h, hpad);
        convw_kernel<<<(3 * Dm * Dm + 255) / 256, 256, 0, stream>>>(conv_w + (long)l * 3 * Dm * Dm, wc);
        {
            dim3 g(Dm / 64, Lq / 64, Bsz);
            gemm_nn<<<g, 256, 0, stream>>>(hpad, Dm, (long)(Lq + 2) * Dm,
                                           wc, Dm, 0L,
                                           tmp, Dm, (long)Lq * Dm,
                                           Lq, Dm, 3 * Dm,
                                           conv_b + (long)l * Dm, nullptr, 0);
        }
        ln_kernel<<<Bsz * Lq, 256, 0, stream>>>(h, tmp, n1s + (long)l * Dm, n1b + (long)l * Dm);

        // qkv
        {
            dim3 g(Dm / 64, (Bsz * Lq) / 64, 1);
            gemm_nn<<<g, 256, 0, stream>>>(h, Dm, 0L, qw + (long)l * Dm * Dm, Dm, 0L,
                                           qv, Dm, 0L, Bsz * Lq, Dm, Dm,
                                           qb + (long)l * Dm, nullptr, 0);
            gemm_nn<<<g, 256, 0, stream>>>(h, Dm, 0L, kw + (long)l * Dm * Dm, Dm, 0L,
                                           kv, Dm, 0L, Bsz * Lq, Dm, Dm,
                                           kb + (long)l * Dm, nullptr, 0);
            gemm_nn<<<g, 256, 0, stream>>>(h, Dm, 0L, vw + (long)l * Dm * Dm, Dm, 0L,
                                           vv, Dm, 0L, Bsz * Lq, Dm, Dm,
                                           vb + (long)l * Dm, nullptr, 0);
        }

        // attention
        {
            dim3 g(Lq / 64, Lq / 64, Bsz * Hh);
            scores_kernel<<<g, 256, 0, stream>>>(qv, kv, scb);
        }
        topk_softmax<<<Bsz * Hh * Lq, 256, 0, stream>>>(scb);
        {
            dim3 g(1, Lq / 64, Bsz * Hh);
            attnv_kernel<<<g, 256, 0, stream>>>(scb, vv, ao);
        }
        {
            dim3 g(Dm / 64, (Bsz * Lq) / 64, 1);
            gemm_nn<<<g, 256, 0, stream>>>(ao, Dm, 0L, ow + (long)l * Dm * Dm, Dm, 0L,
                                           tmp, Dm, 0L, Bsz * Lq, Dm, Dm,
                                           ob + (long)l * Dm, nullptr, 0);
        }
        ln_kernel<<<Bsz * Lq, 256, 0, stream>>>(h, tmp, n2s + (long)l * Dm, n2b + (long)l * Dm);

        // FFN
        {
            dim3 g(DF / 64, (Bsz * Lq) / 64, 1);
            gemm_nn<<<g, 256, 0, stream>>>(h, Dm, 0L, f1w + (long)l * Dm * DF, DF, 0L,
                                           mid, DF, 0L, Bsz * Lq, DF, Dm,
                                           f1b + (long)l * DF, nullptr, 1);
        }
        {
            dim3 g(Dm / 64, (Bsz * Lq) / 64, 1);
            gemm_nn<<<g, 256, 0, stream>>>(mid, DF, 0L, f2w + (long)l * DF * Dm, Dm, 0L,
                                           h, Dm, 0L, Bsz * Lq, Dm, DF,
                                           f2b + (long)l * Dm, h, 0);
        }
    }

    hipMemcpyAsync(d_out, h, (size_t)out_size * sizeof(float), hipMemcpyDeviceToDevice, stream);
}

// Round 3
// 1589.821 us; speedup vs baseline: 2.6461x; 2.6461x over previous
//
#include <hip/hip_runtime.h>
#include <hip/hip_bf16.h>
#include <math.h>

#define Bsz 8
#define Lq  512
#define Dm  512
#define Hh  8
#define El  4
#define DFF 2048
#define NEG (-3.0e38f)

typedef __hip_bfloat16 bf16;
typedef __attribute__((ext_vector_type(8))) short bf16x8;
typedef __attribute__((ext_vector_type(4))) float f32x4;

#define AS1 __attribute__((address_space(1)))
#define AS3 __attribute__((address_space(3)))

// ---------------- workspace layout (BYTE offsets) ----------------
#define B_H     0L            // f32 h                4096x512        8 MB
#define B_TMP   8388608L      // f32 tmp              4096x512        8 MB
#define B_SC    16777216L     // f32 scores 64x512x512 (bf16 probs in place)  64 MB
#define B_HB    83886080L     // bf16 h copy          4096x512        4 MB
#define B_HPAD  88080384L     // bf16 hpad            8x514x512       4.02 MB
#define B_QKV   92291072L     // bf16 qkv             4096x1536      12 MB
#define B_VT    104873984L    // bf16 vT              64x64x512       4 MB
#define B_AO    109068288L    // bf16 attn out        4096x512        4 MB
#define B_MID   113262592L    // bf16 ffn mid         4096x2048      16 MB
#define B_WC    130039808L    // bf16 conv wT         4x512x1536      6 MB
#define B_WQKV  136331264L    // bf16 qkv wT          4x1536x512      6 MB
#define B_WO    142622720L    // bf16 o wT            4x512x512       2 MB
#define B_WF1   144719872L    // bf16 f1 wT           4x2048x512      8 MB
#define B_WF2   153108480L    // bf16 f2 wT           4x512x2048      8 MB
#define B_BIAS  161497088L    // f32 qkv bias cat     4x1536         24 KB
#define B_END   161521664L

// ---------------- input embedding (f32) ----------------
__global__ __launch_bounds__(256) void embed_kernel(
    const float* __restrict__ x, const float* __restrict__ tf,
    const float* __restrict__ in_w, const float* __restrict__ in_b,
    const float* __restrict__ pos_emb, const float* __restrict__ temp_w,
    const float* __restrict__ temp_b, const float* __restrict__ pos_scale,
    const float* __restrict__ temp_scale, float* __restrict__ h)
{
    int bl = blockIdx.x;           // b*512 + l
    int l  = bl & 511;
    __shared__ float xs[64];
    __shared__ float tfs[2];
    int tid = threadIdx.x;
    if (tid < 64) xs[tid] = x[(long)bl * 64 + tid];
    if (tid < 2)  tfs[tid] = tf[(long)bl * 2 + tid];
    __syncthreads();
    float ps = pos_scale[0], ts = temp_scale[0];
    for (int d = tid; d < Dm; d += 256) {
        float acc = in_b[d];
#pragma unroll
        for (int k2 = 0; k2 < 64; k2++) acc += xs[k2] * in_w[k2 * Dm + d];
        acc += ps * pos_emb[(long)l * Dm + d];
        acc += ts * (tfs[0] * temp_w[d] + tfs[1] * temp_w[Dm + d] + temp_b[d]);
        h[(long)bl * Dm + d] = acc;
    }
}

// ---------------- left-pad h by 2 along time -> bf16 ----------------
__global__ __launch_bounds__(256) void pad_kernel(const float* __restrict__ h, bf16* __restrict__ hpad)
{
    long i = (long)blockIdx.x * 256 + threadIdx.x;
    const long total = (long)Bsz * (Lq + 2) * Dm;
    if (i >= total) return;
    int d = (int)(i & 511);
    long rest = i >> 9;
    int t = (int)(rest % (Lq + 2));
    int b = (int)(rest / (Lq + 2));
    float v = (t < 2) ? 0.f : h[((long)b * Lq + (t - 2)) * Dm + d];
    hpad[i] = __float2bfloat16(v);
}

// ---------------- conv weight: [dout][din][kk] -> bf16 BT[dout][kk*512+din] ----------------
__global__ __launch_bounds__(256) void convw_bf(const float* __restrict__ cw, bf16* __restrict__ out)
{
    long i = (long)blockIdx.x * 256 + threadIdx.x;
    const long total = 4L * 512 * 1536;
    if (i >= total) return;
    int din = (int)(i & 511);
    int kk  = (int)((i >> 9) % 3);
    long r  = i / 1536;
    int dout = (int)(r & 511);
    int z    = (int)(r >> 9);
    out[i] = __float2bfloat16(cw[(((long)z * 512 + dout) * 512 + din) * 3 + kk]);
}

// ---------------- generic f32 (K,N) -> bf16 (N,K) transpose, z-batched ----------------
__global__ __launch_bounds__(256) void wtrans(
    const float* __restrict__ in, bf16* __restrict__ out,
    int N, int Kd, long sIn, long sOut)
{
    int z = blockIdx.z;
    int n0 = blockIdx.x * 32, k0 = blockIdx.y * 32;
    int tid = threadIdx.x;
    int tx = tid & 31, ty = tid >> 5;   // ty 0..7
    __shared__ float t[32][33];
#pragma unroll
    for (int p = 0; p < 4; p++)
        t[ty + 8 * p][tx] = in[z * sIn + (long)(k0 + ty + 8 * p) * N + n0 + tx];
    __syncthreads();
#pragma unroll
    for (int p = 0; p < 4; p++)
        out[z * sOut + (long)(n0 + ty + 8 * p) * Kd + k0 + tx] = __float2bfloat16(t[tx][ty + 8 * p]);
}

// ---------------- concat q/k/v biases ----------------
__global__ __launch_bounds__(256) void biascat(
    const float* __restrict__ qb, const float* __restrict__ kb,
    const float* __restrict__ vb, float* __restrict__ out)
{
    int i = blockIdx.x * 256 + threadIdx.x;
    if (i >= 4 * 1536) return;
    int l = i / 1536, j = i - l * 1536;
    float v = (j < 512) ? qb[l * 512 + j] : (j < 1024) ? kb[l * 512 + j - 512] : vb[l * 512 + j - 1024];
    out[i] = v;
}

// ---------------- residual + LayerNorm -> f32 h + bf16 copy ----------------
__global__ __launch_bounds__(256) void ln_kernel(
    float* __restrict__ h, bf16* __restrict__ hb, const float* __restrict__ r,
    const float* __restrict__ sc, const float* __restrict__ bi)
{
    long base = (long)blockIdx.x * Dm;
    int tid = threadIdx.x;
    float v0 = h[base + tid] + r[base + tid];
    float v1 = h[base + tid + 256] + r[base + tid + 256];
    __shared__ float red[16];
    int lane = tid & 63, wid = tid >> 6;
    float s = v0 + v1;
    for (int off = 32; off; off >>= 1) s += __shfl_down(s, off);
    if (!lane) red[wid] = s;
    __syncthreads();
    float mean = (red[0] + red[1] + red[2] + red[3]) * (1.f / 512.f);
    float d0 = v0 - mean, d1 = v1 - mean;
    float vs = d0 * d0 + d1 * d1;
    for (int off = 32; off; off >>= 1) vs += __shfl_down(vs, off);
    if (!lane) red[4 + wid] = vs;
    __syncthreads();
    float var = (red[4] + red[5] + red[6] + red[7]) * (1.f / 512.f);
    float inv = rsqrtf(var + 1e-5f);
    float o0 = d0 * inv * sc[tid] + bi[tid];
    float o1 = d1 * inv * sc[tid + 256] + bi[tid + 256];
    h[base + tid]        = o0;
    h[base + tid + 256]  = o1;
    hb[base + tid]       = __float2bfloat16(o0);
    hb[base + tid + 256] = __float2bfloat16(o1);
}

// ---------------- v transpose: qkv v-part [pos][d] -> vT [z][d][pos] bf16 ----------------
__global__ __launch_bounds__(256) void vtrans(const bf16* __restrict__ qkv, bf16* __restrict__ vT)
{
    int z = blockIdx.y, b = z >> 3, hh = z & 7;
    int pos0 = blockIdx.x * 64;
    __shared__ bf16 T[64][65];
    int tid = threadIdx.x;
    int d = tid & 63, pr = tid >> 6;
    const bf16* src = qkv + ((long)(b * 512 + pos0)) * 1536 + 1024 + hh * 64;
#pragma unroll
    for (int p = 0; p < 16; p++)
        T[pr + 4 * p][d] = src[(long)(pr + 4 * p) * 1536 + d];
    __syncthreads();
    bf16* dst = vT + (long)z * 32768 + pos0;
    int c = tid & 63, dr = tid >> 6;
#pragma unroll
    for (int p = 0; p < 16; p++)
        dst[(long)(dr + 4 * p) * 512 + c] = T[c][dr + 4 * p];
}

// ---------------- MFMA bf16 GEMM: C = A @ B^T, 128x128 tile, BK=32 ----------------
// A: [M][K] bf16 (lda), B: [N][K] bf16 (ldb). per-z offsets: zb*so + zr*si, zb=z/zdiv.
// flags: 1 = skip tiles with bx>by (triangular), 2 = Kend = min(K, m0+128) (causal A).
__global__ __launch_bounds__(256) void mm_bt(
    const bf16* __restrict__ A, int lda, long sAo, long sAi,
    const bf16* __restrict__ B, int ldb, long sBo, long sBi,
    float* __restrict__ Cf, bf16* __restrict__ Cb, int ldc, long sCo, long sCi,
    int K, int zdiv, int Nvalid, int flags,
    const float* __restrict__ bias, const float* __restrict__ Res,
    int relu, float scale)
{
    if ((flags & 1) && blockIdx.x > blockIdx.y) return;
    int z = blockIdx.z;
    int zb = z / zdiv, zr = z - zb * zdiv;
    const bf16* Ap = A + zb * sAo + zr * sAi;
    const bf16* Bp = B + zb * sBo + zr * sBi;
    long cbase = zb * sCo + zr * sCi;
    int m0 = blockIdx.y * 128, n0 = blockIdx.x * 128;
    __shared__ __align__(16) bf16 As[128 * 32];
    __shared__ __align__(16) bf16 Bs[128 * 32];
    int tid = threadIdx.x, wave = tid >> 6, lane = tid & 63;
    int wm = wave >> 1, wn = wave & 1;
    int lr = lane >> 2, lk = (lane & 3) * 8;
    int fm = lane & 15, fq = lane >> 4;
    f32x4 acc[4][4] = {};
    int Kend = (flags & 2) ? ((K < m0 + 128) ? K : (m0 + 128)) : K;
    const bf16* gA0 = Ap + (long)(m0 + wave * 16 + lr) * lda + lk;
    const bf16* gA1 = gA0 + (long)64 * lda;
    const bf16* gB0 = Bp + (long)(n0 + wave * 16 + lr) * ldb + lk;
    const bf16* gB1 = gB0 + (long)64 * ldb;
    bf16* lA0 = As + (wave * 16) * 32;
    bf16* lA1 = As + (64 + wave * 16) * 32;
    bf16* lB0 = Bs + (wave * 16) * 32;
    bf16* lB1 = Bs + (64 + wave * 16) * 32;

    for (int k0 = 0; k0 < Kend; k0 += 32) {
        __syncthreads();
        __builtin_amdgcn_global_load_lds((const AS1 void*)(gA0 + k0), (AS3 void*)lA0, 16, 0, 0);
        __builtin_amdgcn_global_load_lds((const AS1 void*)(gA1 + k0), (AS3 void*)lA1, 16, 0, 0);
        __builtin_amdgcn_global_load_lds((const AS1 void*)(gB0 + k0), (AS3 void*)lB0, 16, 0, 0);
        __builtin_amdgcn_global_load_lds((const AS1 void*)(gB1 + k0), (AS3 void*)lB1, 16, 0, 0);
        __syncthreads();
        bf16x8 af[4], bfr[4];
#pragma unroll
        for (int t = 0; t < 4; t++) {
            af[t]  = *(const bf16x8*)(As + (wm * 64 + t * 16 + fm) * 32 + fq * 8);
            bfr[t] = *(const bf16x8*)(Bs + (wn * 64 + t * 16 + fm) * 32 + fq * 8);
        }
#pragma unroll
        for (int i = 0; i < 4; i++)
#pragma unroll
            for (int j = 0; j < 4; j++)
                acc[i][j] = __builtin_amdgcn_mfma_f32_16x16x32_bf16(af[i], bfr[j], acc[i][j], 0, 0, 0);
    }

#pragma unroll
    for (int i = 0; i < 4; i++) {
        int mrow = m0 + wm * 64 + i * 16 + fq * 4;
#pragma unroll
        for (int j = 0; j < 4; j++) {
            int n = n0 + wn * 64 + j * 16 + fm;
            if (n < Nvalid) {
                float bs = bias ? bias[n] : 0.f;
#pragma unroll
                for (int r = 0; r < 4; r++) {
                    float c = acc[i][j][r] * scale + bs;
                    if (relu) c = fmaxf(c, 0.f);
                    long addr = cbase + (long)(mrow + r) * ldc + n;
                    if (Res) c += Res[addr];
                    if (Cf) Cf[addr] = c;
                    else    Cb[addr] = __float2bfloat16(c);
                }
            }
        }
    }
}

// ---------------- per-row top-k(256) threshold + softmax; bf16 probs in place ----------------
__global__ __launch_bounds__(256) void topk_softmax(float* __restrict__ sc)
{
    int row = blockIdx.x;              // z*512 + q
    int q = row & 511;
    int z = row >> 9;
    float* s = sc + (long)z * (Lq * Lq) + (long)q * Lq;
    __shared__ float srt[512];
    __shared__ float red[16];
    int tid = threadIdx.x;
    int j1 = tid + 256;
    float v0 = (tid <= q) ? s[tid] : NEG;
    float v1 = (j1 <= q) ? s[j1] : NEG;
    float T = NEG;
    if (q >= 256) {                    // need 256th largest among q+1 >= 257 valid
        srt[tid] = v0; srt[j1] = v1;
        for (int ksz = 2; ksz <= 512; ksz <<= 1) {
            for (int jj = ksz >> 1; jj > 0; jj >>= 1) {
                __syncthreads();
                int i = ((tid & ~(jj - 1)) << 1) | (tid & (jj - 1));
                int p = i | jj;
                float a = srt[i], b = srt[p];
                bool asc = ((i & ksz) == 0);
                if ((a > b) == asc) { srt[i] = b; srt[p] = a; }
            }
        }
        __syncthreads();
        T = srt[256];                  // ascending: 256th largest
    }
    int lane = tid & 63, wid = tid >> 6;
    float m = fmaxf(v0, v1);
    for (int off = 32; off; off >>= 1) m = fmaxf(m, __shfl_down(m, off));
    if (!lane) red[wid] = m;
    __syncthreads();
    m = fmaxf(fmaxf(red[0], red[1]), fmaxf(red[2], red[3]));
    bool k0 = (tid <= q) && (v0 >= T);
    bool k1 = (j1 <= q) && (v1 >= T);
    float e0 = k0 ? expf(v0 - m) : 0.f;
    float e1 = k1 ? expf(v1 - m) : 0.f;
    float ssum = e0 + e1;
    for (int off = 32; off; off >>= 1) ssum += __shfl_down(ssum, off);
    if (!lane) red[8 + wid] = ssum;
    __syncthreads();
    float inv = 1.f / (red[8] + red[9] + red[10] + red[11]);
    bf16* sb = (bf16*)s;               // in-place bf16 probs, row stride 1024 bf16
    sb[tid] = __float2bfloat16(e0 * inv);
    sb[j1]  = __float2bfloat16(e1 * inv);
}

extern "C" void kernel_launch(void* const* d_in, const int* in_sizes, int n_in,
                              void* d_out, int out_size, void* d_ws, size_t ws_size,
                              hipStream_t stream)
{
    const float* x         = (const float*)d_in[0];
    const float* tf        = (const float*)d_in[1];
    const float* in_w      = (const float*)d_in[2];
    const float* in_b      = (const float*)d_in[3];
    const float* pos_emb   = (const float*)d_in[4];
    const float* temp_w    = (const float*)d_in[5];
    const float* temp_b    = (const float*)d_in[6];
    const float* pos_scale = (const float*)d_in[7];
    const float* temp_scale= (const float*)d_in[8];
    const float* conv_w    = (const float*)d_in[9];
    const float* conv_b    = (const float*)d_in[10];
    const float* qw        = (const float*)d_in[11];
    const float* qb        = (const float*)d_in[12];
    const float* kw        = (const float*)d_in[13];
    const float* kb        = (const float*)d_in[14];
    const float* vw        = (const float*)d_in[15];
    const float* vb        = (const float*)d_in[16];
    const float* ow        = (const float*)d_in[17];
    const float* ob        = (const float*)d_in[18];
    const float* f1w       = (const float*)d_in[19];
    const float* f1b       = (const float*)d_in[20];
    const float* f2w       = (const float*)d_in[21];
    const float* f2b       = (const float*)d_in[22];
    const float* n1s       = (const float*)d_in[23];
    const float* n1b       = (const float*)d_in[24];
    const float* n2s       = (const float*)d_in[25];
    const float* n2b       = (const float*)d_in[26];

    if (ws_size < (size_t)B_END) return;

    char* wsb = (char*)d_ws;
    float* h    = (float*)(wsb + B_H);
    float* tmp  = (float*)(wsb + B_TMP);
    float* scb  = (float*)(wsb + B_SC);
    bf16*  hb   = (bf16*)(wsb + B_HB);
    bf16*  hpad = (bf16*)(wsb + B_HPAD);
    bf16*  qkv  = (bf16*)(wsb + B_QKV);
    bf16*  vT   = (bf16*)(wsb + B_VT);
    bf16*  ao   = (bf16*)(wsb + B_AO);
    bf16*  mid  = (bf16*)(wsb + B_MID);
    bf16*  wC   = (bf16*)(wsb + B_WC);
    bf16*  wQKV = (bf16*)(wsb + B_WQKV);
    bf16*  wO   = (bf16*)(wsb + B_WO);
    bf16*  wF1  = (bf16*)(wsb + B_WF1);
    bf16*  wF2  = (bf16*)(wsb + B_WF2);
    float* bqkv = (float*)(wsb + B_BIAS);

    // ---- weight prep (every call; cheap) ----
    convw_bf<<<(4 * 512 * 1536) / 256, 256, 0, stream>>>(conv_w, wC);
    {
        dim3 g(16, 16, 4);
        wtrans<<<g, 256, 0, stream>>>(qw, wQKV,            512, 512, 262144L, 786432L);
        wtrans<<<g, 256, 0, stream>>>(kw, wQKV + 262144,   512, 512, 262144L, 786432L);
        wtrans<<<g, 256, 0, stream>>>(vw, wQKV + 524288,   512, 512, 262144L, 786432L);
        wtrans<<<g, 256, 0, stream>>>(ow, wO,              512, 512, 262144L, 262144L);
        dim3 g1(64, 16, 4);
        wtrans<<<g1, 256, 0, stream>>>(f1w, wF1,          2048, 512, 1048576L, 1048576L);
        dim3 g2(16, 64, 4);
        wtrans<<<g2, 256, 0, stream>>>(f2w, wF2,           512, 2048, 1048576L, 1048576L);
    }
    biascat<<<24, 256, 0, stream>>>(qb, kb, vb, bqkv);

    embed_kernel<<<Bsz * Lq, 256, 0, stream>>>(x, tf, in_w, in_b, pos_emb, temp_w, temp_b,
                                               pos_scale, temp_scale, h);

    for (int l = 0; l < El; l++) {
        // causal conv (as GEMM over hpad sliding window, K = 3*512)
        pad_kernel<<<(Bsz * (Lq + 2) * Dm + 255) / 256, 256, 0, stream>>>(h, hpad);
        {
            dim3 g(4, 4, 8);
            mm_bt<<<g, 256, 0, stream>>>(hpad, 512, 263168L, 0L,
                                         wC + (long)l * 786432, 1536, 0L, 0L,
                                         tmp, nullptr, 512, 262144L, 0L,
                                         1536, 1, 512, 0,
                                         conv_b + (long)l * 512, nullptr, 0, 1.f);
        }
        ln_kernel<<<Bsz * Lq, 256, 0, stream>>>(h, hb, tmp, n1s + (long)l * 512, n1b + (long)l * 512);

        // fused QKV: [4096,512] @ [512,1536]
        {
            dim3 g(12, 32, 1);
            mm_bt<<<g, 256, 0, stream>>>(hb, 512, 0L, 0L,
                                         wQKV + (long)l * 786432, 512, 0L, 0L,
                                         nullptr, qkv, 1536, 0L, 0L,
                                         512, 1, 1536, 0,
                                         bqkv + (long)l * 1536, nullptr, 0, 1.f);
        }

        // scores = 0.125 * q @ k^T  (lower-triangle tiles only) -> f32 scb
        {
            dim3 g(4, 4, 64);
            mm_bt<<<g, 256, 0, stream>>>(qkv, 1536, 786432L, 64L,
                                         qkv + 512, 1536, 786432L, 64L,
                                         scb, nullptr, 512, 2097152L, 262144L,
                                         64, 8, 512, 1,
                                         nullptr, nullptr, 0, 0.125f);
        }
        topk_softmax<<<Bsz * Hh * Lq, 256, 0, stream>>>(scb);
        {
            dim3 gv(8, 64, 1);
            vtrans<<<gv, 256, 0, stream>>>(qkv, vT);
        }
        // attn @ v : A = bf16 probs (ld 1024), B = vT [d][pos]; causal K limit
        {
            dim3 g(1, 4, 64);
            mm_bt<<<g, 256, 0, stream>>>((const bf16*)scb, 1024, 4194304L, 524288L,
                                         vT, 512, 262144L, 32768L,
                                         nullptr, ao, 512, 262144L, 64L,
                                         512, 8, 64, 2,
                                         nullptr, nullptr, 0, 1.f);
        }
        // out proj
        {
            dim3 g(4, 32, 1);
            mm_bt<<<g, 256, 0, stream>>>(ao, 512, 0L, 0L,
                                         wO + (long)l * 262144, 512, 0L, 0L,
                                         tmp, nullptr, 512, 0L, 0L,
                                         512, 1, 512, 0,
                                         ob + (long)l * 512, nullptr, 0, 1.f);
        }
        ln_kernel<<<Bsz * Lq, 256, 0, stream>>>(h, hb, tmp, n2s + (long)l * 512, n2b + (long)l * 512);

        // FFN1 (relu) -> bf16 mid
        {
            dim3 g(16, 32, 1);
            mm_bt<<<g, 256, 0, stream>>>(hb, 512, 0L, 0L,
                                         wF1 + (long)l * 1048576, 512, 0L, 0L,
                                         nullptr, mid, 2048, 0L, 0L,
                                         512, 1, 2048, 0,
                                         f1b + (long)l * 2048, nullptr, 1, 1.f);
        }
        // FFN2 + residual -> f32 h
        {
            dim3 g(4, 32, 1);
            mm_bt<<<g, 256, 0, stream>>>(mid, 2048, 0L, 0L,
                                         wF2 + (long)l * 1048576, 2048, 0L, 0L,
                                         h, nullptr, 512, 0L, 0L,
                                         2048, 1, 512, 0,
                                         f2b + (long)l * 512, h, 0, 1.f);
        }
    }

    hipMemcpyAsync(d_out, h, (size_t)out_size * sizeof(float), hipMemcpyDeviceToDevice, stream);
}

// Round 4
// 1470.099 us; speedup vs baseline: 2.8616x; 1.0814x over previous
//
#include <hip/hip_runtime.h>
#include <hip/hip_bf16.h>
#include <math.h>

#define Bsz 8
#define Lq  512
#define Dm  512
#define Hh  8
#define El  4
#define DFF 2048
#define NEG (-3.0e38f)

typedef __hip_bfloat16 bf16;
typedef __attribute__((ext_vector_type(8))) short bf16x8;
typedef __attribute__((ext_vector_type(4))) float f32x4;

#define AS1 __attribute__((address_space(1)))
#define AS3 __attribute__((address_space(3)))

// ---------------- workspace layout (BYTE offsets) ----------------
#define B_H     0L            // f32 h                4096x512        8 MB
#define B_TMP   8388608L      // f32 tmp              4096x512        8 MB
#define B_SC    16777216L     // f32 scores 64x512x512 (bf16 probs in place)  64 MB
#define B_HB    83886080L     // bf16 h copy          4096x512        4 MB
#define B_HPAD  88080384L     // bf16 hpad            8x514x512       4.02 MB
#define B_QKV   92291072L     // bf16 qkv             4096x1536      12 MB
#define B_VT    104873984L    // bf16 vT              64x64x512       4 MB
#define B_AO    109068288L    // bf16 attn out        4096x512        4 MB
#define B_MID   113262592L    // bf16 ffn mid         4096x2048      16 MB
#define B_WC    130039808L    // bf16 conv wT         4x512x1536      6 MB
#define B_WQKV  136331264L    // bf16 qkv wT          4x1536x512      6 MB
#define B_WO    142622720L    // bf16 o wT            4x512x512       2 MB
#define B_WF1   144719872L    // bf16 f1 wT           4x2048x512      8 MB
#define B_WF2   153108480L    // bf16 f2 wT           4x512x2048      8 MB
#define B_BIAS  161497088L    // f32 qkv bias cat     4x1536         24 KB
#define B_END   161521664L

// ---------------- input embedding (f32) ----------------
__global__ __launch_bounds__(256) void embed_kernel(
    const float* __restrict__ x, const float* __restrict__ tf,
    const float* __restrict__ in_w, const float* __restrict__ in_b,
    const float* __restrict__ pos_emb, const float* __restrict__ temp_w,
    const float* __restrict__ temp_b, const float* __restrict__ pos_scale,
    const float* __restrict__ temp_scale, float* __restrict__ h)
{
    int bl = blockIdx.x;           // b*512 + l
    int l  = bl & 511;
    __shared__ float xs[64];
    __shared__ float tfs[2];
    int tid = threadIdx.x;
    if (tid < 64) xs[tid] = x[(long)bl * 64 + tid];
    if (tid < 2)  tfs[tid] = tf[(long)bl * 2 + tid];
    __syncthreads();
    float ps = pos_scale[0], ts = temp_scale[0];
    for (int d = tid; d < Dm; d += 256) {
        float acc = in_b[d];
#pragma unroll
        for (int k2 = 0; k2 < 64; k2++) acc += xs[k2] * in_w[k2 * Dm + d];
        acc += ps * pos_emb[(long)l * Dm + d];
        acc += ts * (tfs[0] * temp_w[d] + tfs[1] * temp_w[Dm + d] + temp_b[d]);
        h[(long)bl * Dm + d] = acc;
    }
}

// ---------------- left-pad h by 2 along time -> bf16 ----------------
__global__ __launch_bounds__(256) void pad_kernel(const float* __restrict__ h, bf16* __restrict__ hpad)
{
    long i = (long)blockIdx.x * 256 + threadIdx.x;
    const long total = (long)Bsz * (Lq + 2) * Dm;
    if (i >= total) return;
    int d = (int)(i & 511);
    long rest = i >> 9;
    int t = (int)(rest % (Lq + 2));
    int b = (int)(rest / (Lq + 2));
    float v = (t < 2) ? 0.f : h[((long)b * Lq + (t - 2)) * Dm + d];
    hpad[i] = __float2bfloat16(v);
}

// ---------------- conv weight: [dout][din][kk] -> bf16 BT[dout][kk*512+din] ----------------
__global__ __launch_bounds__(256) void convw_bf(const float* __restrict__ cw, bf16* __restrict__ out)
{
    long i = (long)blockIdx.x * 256 + threadIdx.x;
    const long total = 4L * 512 * 1536;
    if (i >= total) return;
    int din = (int)(i & 511);
    int kk  = (int)((i >> 9) % 3);
    long r  = i / 1536;
    int dout = (int)(r & 511);
    int z    = (int)(r >> 9);
    out[i] = __float2bfloat16(cw[(((long)z * 512 + dout) * 512 + din) * 3 + kk]);
}

// ---------------- generic f32 (K,N) -> bf16 (N,K) transpose, z-batched ----------------
__global__ __launch_bounds__(256) void wtrans(
    const float* __restrict__ in, bf16* __restrict__ out,
    int N, int Kd, long sIn, long sOut)
{
    int z = blockIdx.z;
    int n0 = blockIdx.x * 32, k0 = blockIdx.y * 32;
    int tid = threadIdx.x;
    int tx = tid & 31, ty = tid >> 5;   // ty 0..7
    __shared__ float t[32][33];
#pragma unroll
    for (int p = 0; p < 4; p++)
        t[ty + 8 * p][tx] = in[z * sIn + (long)(k0 + ty + 8 * p) * N + n0 + tx];
    __syncthreads();
#pragma unroll
    for (int p = 0; p < 4; p++)
        out[z * sOut + (long)(n0 + ty + 8 * p) * Kd + k0 + tx] = __float2bfloat16(t[tx][ty + 8 * p]);
}

// ---------------- concat q/k/v biases ----------------
__global__ __launch_bounds__(256) void biascat(
    const float* __restrict__ qb, const float* __restrict__ kb,
    const float* __restrict__ vb, float* __restrict__ out)
{
    int i = blockIdx.x * 256 + threadIdx.x;
    if (i >= 4 * 1536) return;
    int l = i / 1536, j = i - l * 1536;
    float v = (j < 512) ? qb[l * 512 + j] : (j < 1024) ? kb[l * 512 + j - 512] : vb[l * 512 + j - 1024];
    out[i] = v;
}

// ---------------- residual + LayerNorm -> f32 h + bf16 copy ----------------
__global__ __launch_bounds__(256) void ln_kernel(
    float* __restrict__ h, bf16* __restrict__ hb, const float* __restrict__ r,
    const float* __restrict__ sc, const float* __restrict__ bi)
{
    long base = (long)blockIdx.x * Dm;
    int tid = threadIdx.x;
    float v0 = h[base + tid] + r[base + tid];
    float v1 = h[base + tid + 256] + r[base + tid + 256];
    __shared__ float red[16];
    int lane = tid & 63, wid = tid >> 6;
    float s = v0 + v1;
    for (int off = 32; off; off >>= 1) s += __shfl_down(s, off);
    if (!lane) red[wid] = s;
    __syncthreads();
    float mean = (red[0] + red[1] + red[2] + red[3]) * (1.f / 512.f);
    float d0 = v0 - mean, d1 = v1 - mean;
    float vs = d0 * d0 + d1 * d1;
    for (int off = 32; off; off >>= 1) vs += __shfl_down(vs, off);
    if (!lane) red[4 + wid] = vs;
    __syncthreads();
    float var = (red[4] + red[5] + red[6] + red[7]) * (1.f / 512.f);
    float inv = rsqrtf(var + 1e-5f);
    float o0 = d0 * inv * sc[tid] + bi[tid];
    float o1 = d1 * inv * sc[tid + 256] + bi[tid + 256];
    h[base + tid]        = o0;
    h[base + tid + 256]  = o1;
    hb[base + tid]       = __float2bfloat16(o0);
    hb[base + tid + 256] = __float2bfloat16(o1);
}

// ---------------- v transpose: qkv v-part [pos][d] -> vT [z][d][pos] bf16 ----------------
__global__ __launch_bounds__(256) void vtrans(const bf16* __restrict__ qkv, bf16* __restrict__ vT)
{
    int z = blockIdx.y, b = z >> 3, hh = z & 7;
    int pos0 = blockIdx.x * 64;
    __shared__ bf16 T[64][65];
    int tid = threadIdx.x;
    int d = tid & 63, pr = tid >> 6;
    const bf16* src = qkv + ((long)(b * 512 + pos0)) * 1536 + 1024 + hh * 64;
#pragma unroll
    for (int p = 0; p < 16; p++)
        T[pr + 4 * p][d] = src[(long)(pr + 4 * p) * 1536 + d];
    __syncthreads();
    bf16* dst = vT + (long)z * 32768 + pos0;
    int c = tid & 63, dr = tid >> 6;
#pragma unroll
    for (int p = 0; p < 16; p++)
        dst[(long)(dr + 4 * p) * 512 + c] = T[c][dr + 4 * p];
}

// ---------------- MFMA bf16 GEMM: C = A @ B^T, 128x128 tile, BK=32 ----------------
// A: [M][K] bf16 (lda), B: [N][K] bf16 (ldb). per-z offsets: zb*so + zr*si, zb=z/zdiv.
// flags: 1 = skip tiles with bx>by (triangular), 2 = Kend = min(K, m0+128) (causal A).
__global__ __launch_bounds__(256) void mm_bt(
    const bf16* __restrict__ A, int lda, long sAo, long sAi,
    const bf16* __restrict__ B, int ldb, long sBo, long sBi,
    float* __restrict__ Cf, bf16* __restrict__ Cb, int ldc, long sCo, long sCi,
    int K, int zdiv, int Nvalid, int flags,
    const float* __restrict__ bias, const float* __restrict__ Res,
    int relu, float scale)
{
    if ((flags & 1) && blockIdx.x > blockIdx.y) return;
    int z = blockIdx.z;
    int zb = z / zdiv, zr = z - zb * zdiv;
    const bf16* Ap = A + zb * sAo + zr * sAi;
    const bf16* Bp = B + zb * sBo + zr * sBi;
    long cbase = zb * sCo + zr * sCi;
    int m0 = blockIdx.y * 128, n0 = blockIdx.x * 128;
    __shared__ __align__(16) bf16 As[128 * 32];
    __shared__ __align__(16) bf16 Bs[128 * 32];
    int tid = threadIdx.x, wave = tid >> 6, lane = tid & 63;
    int wm = wave >> 1, wn = wave & 1;
    int lr = lane >> 2, lk = (lane & 3) * 8;
    int fm = lane & 15, fq = lane >> 4;
    bool nact = (n0 + wn * 64) < Nvalid;   // this wave's 64-col slice is real
    f32x4 acc[4][4] = {};
    int Kend = (flags & 2) ? ((K < m0 + 128) ? K : (m0 + 128)) : K;
    const bf16* gA0 = Ap + (long)(m0 + wave * 16 + lr) * lda + lk;
    const bf16* gA1 = gA0 + (long)64 * lda;
    const bf16* gB0 = Bp + (long)(n0 + wave * 16 + lr) * ldb + lk;
    const bf16* gB1 = gB0 + (long)64 * ldb;
    bf16* lA0 = As + (wave * 16) * 32;
    bf16* lA1 = As + (64 + wave * 16) * 32;
    bf16* lB0 = Bs + (wave * 16) * 32;
    bf16* lB1 = Bs + (64 + wave * 16) * 32;

    for (int k0 = 0; k0 < Kend; k0 += 32) {
        __syncthreads();
        __builtin_amdgcn_global_load_lds((const AS1 void*)(gA0 + k0), (AS3 void*)lA0, 16, 0, 0);
        __builtin_amdgcn_global_load_lds((const AS1 void*)(gA1 + k0), (AS3 void*)lA1, 16, 0, 0);
        __builtin_amdgcn_global_load_lds((const AS1 void*)(gB0 + k0), (AS3 void*)lB0, 16, 0, 0);
        __builtin_amdgcn_global_load_lds((const AS1 void*)(gB1 + k0), (AS3 void*)lB1, 16, 0, 0);
        __syncthreads();
        if (nact) {
            bf16x8 af[4], bfr[4];
#pragma unroll
            for (int t = 0; t < 4; t++) {
                af[t]  = *(const bf16x8*)(As + (wm * 64 + t * 16 + fm) * 32 + fq * 8);
                bfr[t] = *(const bf16x8*)(Bs + (wn * 64 + t * 16 + fm) * 32 + fq * 8);
            }
#pragma unroll
            for (int i = 0; i < 4; i++)
#pragma unroll
                for (int j = 0; j < 4; j++)
                    acc[i][j] = __builtin_amdgcn_mfma_f32_16x16x32_bf16(af[i], bfr[j], acc[i][j], 0, 0, 0);
        }
    }

    if (!nact) return;
#pragma unroll
    for (int i = 0; i < 4; i++) {
        int mrow = m0 + wm * 64 + i * 16 + fq * 4;
#pragma unroll
        for (int j = 0; j < 4; j++) {
            int n = n0 + wn * 64 + j * 16 + fm;
            if (n < Nvalid) {
                float bs = bias ? bias[n] : 0.f;
#pragma unroll
                for (int r = 0; r < 4; r++) {
                    float c = acc[i][j][r] * scale + bs;
                    if (relu) c = fmaxf(c, 0.f);
                    long addr = cbase + (long)(mrow + r) * ldc + n;
                    if (Res) c += Res[addr];
                    if (Cf) Cf[addr] = c;
                    else    Cb[addr] = __float2bfloat16(c);
                }
            }
        }
    }
}

// ---------------- per-row top-k(256) via exact radix-select + softmax; bf16 probs in place --------
__global__ __launch_bounds__(256) void topk_softmax(float* __restrict__ sc)
{
    int row = blockIdx.x;              // z*512 + q
    int q = row & 511;
    int z = row >> 9;
    float* s = sc + (long)z * (Lq * Lq) + (long)q * Lq;
    __shared__ int hist[256];
    __shared__ float red[16];
    __shared__ unsigned sh_prefix;
    __shared__ int sh_k;
    int tid = threadIdx.x;
    int j1 = tid + 256;
    bool val0 = (tid <= q), val1 = (j1 <= q);
    float v0 = val0 ? s[tid] : NEG;
    float v1 = val1 ? s[j1] : NEG;
    // monotonic sortable keys (bigger float -> bigger unsigned key)
    unsigned u0 = __float_as_uint(v0);
    unsigned u1 = __float_as_uint(v1);
    unsigned key0 = u0 ^ (unsigned)(((int)u0 >> 31) | 0x80000000);
    unsigned key1 = u1 ^ (unsigned)(((int)u1 >> 31) | 0x80000000);
    unsigned Tkey = 0u;
    if (q >= 256) {                    // exact 256th-largest key via 4x8-bit radix select
        unsigned prefix = 0u, pmask = 0u;
        int kneed = 256;
#pragma unroll
        for (int shift = 24; shift >= 0; shift -= 8) {
            hist[tid] = 0;
            __syncthreads();
            if (val0 && (key0 & pmask) == prefix) atomicAdd(&hist[(key0 >> shift) & 255], 1);
            if (val1 && (key1 & pmask) == prefix) atomicAdd(&hist[(key1 >> shift) & 255], 1);
            __syncthreads();
            if (tid < 64) {            // wave 0: reverse suffix-scan over 64 groups of 4 buckets
                int b4 = tid * 4;
                int s0 = hist[b4], s1 = hist[b4 + 1], s2 = hist[b4 + 2], s3 = hist[b4 + 3];
                int tot = s0 + s1 + s2 + s3;
                int run = tot;
#pragma unroll
                for (int off = 1; off < 64; off <<= 1) {
                    int o = __shfl_down(run, off);
                    if (tid + off < 64) run += o;
                }
                int above = run - tot;                 // count in groups strictly above
                if (above < kneed && kneed <= above + tot) {
                    int c3 = above + s3;
                    int c2 = c3 + s2;
                    int c1 = c2 + s1;
                    int dsel, rem;
                    if (kneed <= c3)      { dsel = b4 + 3; rem = kneed - above; }
                    else if (kneed <= c2) { dsel = b4 + 2; rem = kneed - c3; }
                    else if (kneed <= c1) { dsel = b4 + 1; rem = kneed - c2; }
                    else                  { dsel = b4;     rem = kneed - c1; }
                    sh_prefix = prefix | ((unsigned)dsel << shift);
                    sh_k = rem;
                }
            }
            __syncthreads();
            prefix = sh_prefix;
            kneed  = sh_k;
            pmask |= (0xFFu << shift);
            __syncthreads();
        }
        Tkey = prefix;                 // exact key of the 256th largest
    }
    int lane = tid & 63, wid = tid >> 6;
    float m = fmaxf(v0, v1);
    for (int off = 32; off; off >>= 1) m = fmaxf(m, __shfl_down(m, off));
    if (!lane) red[wid] = m;
    __syncthreads();
    m = fmaxf(fmaxf(red[0], red[1]), fmaxf(red[2], red[3]));
    bool k0 = val0 && (key0 >= Tkey);
    bool k1 = val1 && (key1 >= Tkey);
    float e0 = k0 ? expf(v0 - m) : 0.f;
    float e1 = k1 ? expf(v1 - m) : 0.f;
    float ssum = e0 + e1;
    for (int off = 32; off; off >>= 1) ssum += __shfl_down(ssum, off);
    if (!lane) red[8 + wid] = ssum;
    __syncthreads();
    float inv = 1.f / (red[8] + red[9] + red[10] + red[11]);
    bf16* sb = (bf16*)s;               // in-place bf16 probs, row stride 1024 bf16
    sb[tid] = __float2bfloat16(e0 * inv);
    sb[j1]  = __float2bfloat16(e1 * inv);
}

extern "C" void kernel_launch(void* const* d_in, const int* in_sizes, int n_in,
                              void* d_out, int out_size, void* d_ws, size_t ws_size,
                              hipStream_t stream)
{
    const float* x         = (const float*)d_in[0];
    const float* tf        = (const float*)d_in[1];
    const float* in_w      = (const float*)d_in[2];
    const float* in_b      = (const float*)d_in[3];
    const float* pos_emb   = (const float*)d_in[4];
    const float* temp_w    = (const float*)d_in[5];
    const float* temp_b    = (const float*)d_in[6];
    const float* pos_scale = (const float*)d_in[7];
    const float* temp_scale= (const float*)d_in[8];
    const float* conv_w    = (const float*)d_in[9];
    const float* conv_b    = (const float*)d_in[10];
    const float* qw        = (const float*)d_in[11];
    const float* qb        = (const float*)d_in[12];
    const float* kw        = (const float*)d_in[13];
    const float* kb        = (const float*)d_in[14];
    const float* vw        = (const float*)d_in[15];
    const float* vb        = (const float*)d_in[16];
    const float* ow        = (const float*)d_in[17];
    const float* ob        = (const float*)d_in[18];
    const float* f1w       = (const float*)d_in[19];
    const float* f1b       = (const float*)d_in[20];
    const float* f2w       = (const float*)d_in[21];
    const float* f2b       = (const float*)d_in[22];
    const float* n1s       = (const float*)d_in[23];
    const float* n1b       = (const float*)d_in[24];
    const float* n2s       = (const float*)d_in[25];
    const float* n2b       = (const float*)d_in[26];

    if (ws_size < (size_t)B_END) return;

    char* wsb = (char*)d_ws;
    float* h    = (float*)(wsb + B_H);
    float* tmp  = (float*)(wsb + B_TMP);
    float* scb  = (float*)(wsb + B_SC);
    bf16*  hb   = (bf16*)(wsb + B_HB);
    bf16*  hpad = (bf16*)(wsb + B_HPAD);
    bf16*  qkv  = (bf16*)(wsb + B_QKV);
    bf16*  vT   = (bf16*)(wsb + B_VT);
    bf16*  ao   = (bf16*)(wsb + B_AO);
    bf16*  mid  = (bf16*)(wsb + B_MID);
    bf16*  wC   = (bf16*)(wsb + B_WC);
    bf16*  wQKV = (bf16*)(wsb + B_WQKV);
    bf16*  wO   = (bf16*)(wsb + B_WO);
    bf16*  wF1  = (bf16*)(wsb + B_WF1);
    bf16*  wF2  = (bf16*)(wsb + B_WF2);
    float* bqkv = (float*)(wsb + B_BIAS);

    // ---- weight prep (every call; cheap) ----
    convw_bf<<<(4 * 512 * 1536) / 256, 256, 0, stream>>>(conv_w, wC);
    {
        dim3 g(16, 16, 4);
        wtrans<<<g, 256, 0, stream>>>(qw, wQKV,            512, 512, 262144L, 786432L);
        wtrans<<<g, 256, 0, stream>>>(kw, wQKV + 262144,   512, 512, 262144L, 786432L);
        wtrans<<<g, 256, 0, stream>>>(vw, wQKV + 524288,   512, 512, 262144L, 786432L);
        wtrans<<<g, 256, 0, stream>>>(ow, wO,              512, 512, 262144L, 262144L);
        dim3 g1(64, 16, 4);
        wtrans<<<g1, 256, 0, stream>>>(f1w, wF1,          2048, 512, 1048576L, 1048576L);
        dim3 g2(16, 64, 4);
        wtrans<<<g2, 256, 0, stream>>>(f2w, wF2,           512, 2048, 1048576L, 1048576L);
    }
    biascat<<<24, 256, 0, stream>>>(qb, kb, vb, bqkv);

    embed_kernel<<<Bsz * Lq, 256, 0, stream>>>(x, tf, in_w, in_b, pos_emb, temp_w, temp_b,
                                               pos_scale, temp_scale, h);

    for (int l = 0; l < El; l++) {
        // causal conv (as GEMM over hpad sliding window, K = 3*512)
        pad_kernel<<<(Bsz * (Lq + 2) * Dm + 255) / 256, 256, 0, stream>>>(h, hpad);
        {
            dim3 g(4, 4, 8);
            mm_bt<<<g, 256, 0, stream>>>(hpad, 512, 263168L, 0L,
                                         wC + (long)l * 786432, 1536, 0L, 0L,
                                         tmp, nullptr, 512, 262144L, 0L,
                                         1536, 1, 512, 0,
                                         conv_b + (long)l * 512, nullptr, 0, 1.f);
        }
        ln_kernel<<<Bsz * Lq, 256, 0, stream>>>(h, hb, tmp, n1s + (long)l * 512, n1b + (long)l * 512);

        // fused QKV: [4096,512] @ [512,1536]
        {
            dim3 g(12, 32, 1);
            mm_bt<<<g, 256, 0, stream>>>(hb, 512, 0L, 0L,
                                         wQKV + (long)l * 786432, 512, 0L, 0L,
                                         nullptr, qkv, 1536, 0L, 0L,
                                         512, 1, 1536, 0,
                                         bqkv + (long)l * 1536, nullptr, 0, 1.f);
        }

        // scores = 0.125 * q @ k^T  (lower-triangle tiles only) -> f32 scb
        {
            dim3 g(4, 4, 64);
            mm_bt<<<g, 256, 0, stream>>>(qkv, 1536, 786432L, 64L,
                                         qkv + 512, 1536, 786432L, 64L,
                                         scb, nullptr, 512, 2097152L, 262144L,
                                         64, 8, 512, 1,
                                         nullptr, nullptr, 0, 0.125f);
        }
        topk_softmax<<<Bsz * Hh * Lq, 256, 0, stream>>>(scb);
        {
            dim3 gv(8, 64, 1);
            vtrans<<<gv, 256, 0, stream>>>(qkv, vT);
        }
        // attn @ v : A = bf16 probs (ld 1024), B = vT [d][pos]; causal K limit
        {
            dim3 g(1, 4, 64);
            mm_bt<<<g, 256, 0, stream>>>((const bf16*)scb, 1024, 4194304L, 524288L,
                                         vT, 512, 262144L, 32768L,
                                         nullptr, ao, 512, 262144L, 64L,
                                         512, 8, 64, 2,
                                         nullptr, nullptr, 0, 1.f);
        }
        // out proj
        {
            dim3 g(4, 32, 1);
            mm_bt<<<g, 256, 0, stream>>>(ao, 512, 0L, 0L,
                                         wO + (long)l * 262144, 512, 0L, 0L,
                                         tmp, nullptr, 512, 0L, 0L,
                                         512, 1, 512, 0,
                                         ob + (long)l * 512, nullptr, 0, 1.f);
        }
        ln_kernel<<<Bsz * Lq, 256, 0, stream>>>(h, hb, tmp, n2s + (long)l * 512, n2b + (long)l * 512);

        // FFN1 (relu) -> bf16 mid
        {
            dim3 g(16, 32, 1);
            mm_bt<<<g, 256, 0, stream>>>(hb, 512, 0L, 0L,
                                         wF1 + (long)l * 1048576, 512, 0L, 0L,
                                         nullptr, mid, 2048, 0L, 0L,
                                         512, 1, 2048, 0,
                                         f1b + (long)l * 2048, nullptr, 1, 1.f);
        }
        // FFN2 + residual -> f32 h
        {
            dim3 g(4, 32, 1);
            mm_bt<<<g, 256, 0, stream>>>(mid, 2048, 0L, 0L,
                                         wF2 + (long)l * 1048576, 2048, 0L, 0L,
                                         h, nullptr, 512, 0L, 0L,
                                         2048, 1, 512, 0,
                                         f2b + (long)l * 512, h, 0, 1.f);
        }
    }

    hipMemcpyAsync(d_out, h, (size_t)out_size * sizeof(float), hipMemcpyDeviceToDevice, stream);
}

// Round 5
// 1408.150 us; speedup vs baseline: 2.9875x; 1.0440x over previous
//
#include <hip/hip_runtime.h>
#include <hip/hip_bf16.h>
#include <math.h>

#define Bsz 8
#define Lq  512
#define Dm  512
#define Hh  8
#define El  4
#define DFF 2048
#define NEG (-3.0e38f)

typedef __hip_bfloat16 bf16;
typedef __attribute__((ext_vector_type(8))) short bf16x8;
typedef __attribute__((ext_vector_type(4))) float f32x4;

#define AS1 __attribute__((address_space(1)))
#define AS3 __attribute__((address_space(3)))

// ---------------- workspace layout (BYTE offsets) ----------------
#define B_H     0L            // f32 h                4096x512        8 MB
#define B_TMP   8388608L      // f32 tmp              4096x512        8 MB
#define B_SC    16777216L     // f32 scores 64x512x512 (bf16 probs in place); also extras at t=0  64 MB
#define B_HB    83886080L     // bf16 xb (512KB) + bf16 in_wT (64KB)  (embed prep)  4 MB region
#define B_HPAD  88080384L     // bf16 hbp padded h    8x514x512       4.21 MB
#define B_QKV   92291072L     // bf16 qkv             4096x1536      12 MB
#define B_VT    104873984L    // bf16 vT              64x64x512       4 MB
#define B_AO    109068288L    // bf16 attn out        4096x512        4 MB
#define B_MID   113262592L    // bf16 ffn mid         4096x2048      16 MB
#define B_WC    130039808L    // bf16 conv wT         4x512x1536      6 MB
#define B_WQKV  136331264L    // bf16 qkv wT          4x1536x512      6 MB
#define B_WO    142622720L    // bf16 o wT            4x512x512       2 MB
#define B_WF1   144719872L    // bf16 f1 wT           4x2048x512      8 MB
#define B_WF2   153108480L    // bf16 f2 wT           4x512x2048      8 MB
#define B_BIAS  161497088L    // f32 qkv bias cat     4x1536         24 KB
#define B_END   161521664L

// ---------------- zero the 2 pad rows per batch in hbp ----------------
__global__ __launch_bounds__(256) void zpad(bf16* __restrict__ hbp)
{
    int i = blockIdx.x * 256 + threadIdx.x;    // 8 batches x 2 rows x 512
    if (i < 8192) {
        int b = i >> 10, r = i & 1023;
        hbp[(long)b * 263168 + r] = __float2bfloat16(0.f);
    }
}

// ---------------- embed prep: cast x->bf16, extras = in_b + ps*pos + ts*(tf@tw+tb) ----------------
__global__ __launch_bounds__(256) void prep_embed(
    const float* __restrict__ x, const float* __restrict__ tf,
    const float* __restrict__ in_b, const float* __restrict__ pos_emb,
    const float* __restrict__ temp_w, const float* __restrict__ temp_b,
    const float* __restrict__ pos_scale, const float* __restrict__ temp_scale,
    bf16* __restrict__ xb, float* __restrict__ extras)
{
    int bl = blockIdx.x, l = bl & 511, tid = threadIdx.x;
    if (tid < 64) xb[(long)bl * 64 + tid] = __float2bfloat16(x[(long)bl * 64 + tid]);
    float ps = pos_scale[0], ts = temp_scale[0];
    float t0 = tf[(long)bl * 2], t1 = tf[(long)bl * 2 + 1];
    for (int d = tid; d < 512; d += 256)
        extras[(long)bl * 512 + d] = in_b[d] + ps * pos_emb[(long)l * 512 + d]
                                   + ts * (t0 * temp_w[d] + t1 * temp_w[512 + d] + temp_b[d]);
}

// ---------------- conv weight: [dout][din][kk] -> bf16 BT[dout][kk*512+din] ----------------
__global__ __launch_bounds__(256) void convw_bf(const float* __restrict__ cw, bf16* __restrict__ out)
{
    long i = (long)blockIdx.x * 256 + threadIdx.x;
    const long total = 4L * 512 * 1536;
    if (i >= total) return;
    int din = (int)(i & 511);
    int kk  = (int)((i >> 9) % 3);
    long r  = i / 1536;
    int dout = (int)(r & 511);
    int z    = (int)(r >> 9);
    out[i] = __float2bfloat16(cw[(((long)z * 512 + dout) * 512 + din) * 3 + kk]);
}

// ---------------- generic f32 (K,N) -> bf16 (N,K) transpose, z-batched ----------------
__global__ __launch_bounds__(256) void wtrans(
    const float* __restrict__ in, bf16* __restrict__ out,
    int N, int Kd, long sIn, long sOut)
{
    int z = blockIdx.z;
    int n0 = blockIdx.x * 32, k0 = blockIdx.y * 32;
    int tid = threadIdx.x;
    int tx = tid & 31, ty = tid >> 5;   // ty 0..7
    __shared__ float t[32][33];
#pragma unroll
    for (int p = 0; p < 4; p++)
        t[ty + 8 * p][tx] = in[z * sIn + (long)(k0 + ty + 8 * p) * N + n0 + tx];
    __syncthreads();
#pragma unroll
    for (int p = 0; p < 4; p++)
        out[z * sOut + (long)(n0 + ty + 8 * p) * Kd + k0 + tx] = __float2bfloat16(t[tx][ty + 8 * p]);
}

// ---------------- concat q/k/v biases ----------------
__global__ __launch_bounds__(256) void biascat(
    const float* __restrict__ qb, const float* __restrict__ kb,
    const float* __restrict__ vb, float* __restrict__ out)
{
    int i = blockIdx.x * 256 + threadIdx.x;
    if (i >= 4 * 1536) return;
    int l = i / 1536, j = i - l * 1536;
    float v = (j < 512) ? qb[l * 512 + j] : (j < 1024) ? kb[l * 512 + j - 512] : vb[l * 512 + j - 1024];
    out[i] = v;
}

// ---------------- residual + LayerNorm -> f32 h + bf16 copy into padded hbp ----------------
__global__ __launch_bounds__(256) void ln_kernel(
    float* __restrict__ h, bf16* __restrict__ hbp, const float* __restrict__ r,
    const float* __restrict__ sc, const float* __restrict__ bi)
{
    long base = (long)blockIdx.x * Dm;
    int b = blockIdx.x >> 9;
    long hbase = base + (long)(b + 1) * 1024;   // hbp row = bl + 2*b + 2
    int tid = threadIdx.x;
    float v0 = h[base + tid] + r[base + tid];
    float v1 = h[base + tid + 256] + r[base + tid + 256];
    __shared__ float red[16];
    int lane = tid & 63, wid = tid >> 6;
    float s = v0 + v1;
    for (int off = 32; off; off >>= 1) s += __shfl_down(s, off);
    if (!lane) red[wid] = s;
    __syncthreads();
    float mean = (red[0] + red[1] + red[2] + red[3]) * (1.f / 512.f);
    float d0 = v0 - mean, d1 = v1 - mean;
    float vs = d0 * d0 + d1 * d1;
    for (int off = 32; off; off >>= 1) vs += __shfl_down(vs, off);
    if (!lane) red[4 + wid] = vs;
    __syncthreads();
    float var = (red[4] + red[5] + red[6] + red[7]) * (1.f / 512.f);
    float inv = rsqrtf(var + 1e-5f);
    float o0 = d0 * inv * sc[tid] + bi[tid];
    float o1 = d1 * inv * sc[tid + 256] + bi[tid + 256];
    h[base + tid]         = o0;
    h[base + tid + 256]   = o1;
    hbp[hbase + tid]       = __float2bfloat16(o0);
    hbp[hbase + tid + 256] = __float2bfloat16(o1);
}

// ---------------- v transpose: qkv v-part [pos][d] -> vT [z][d][pos] bf16 ----------------
__global__ __launch_bounds__(256) void vtrans(const bf16* __restrict__ qkv, bf16* __restrict__ vT)
{
    int z = blockIdx.y, b = z >> 3, hh = z & 7;
    int pos0 = blockIdx.x * 64;
    __shared__ bf16 T[64][65];
    int tid = threadIdx.x;
    int d = tid & 63, pr = tid >> 6;
    const bf16* src = qkv + ((long)(b * 512 + pos0)) * 1536 + 1024 + hh * 64;
#pragma unroll
    for (int p = 0; p < 16; p++)
        T[pr + 4 * p][d] = src[(long)(pr + 4 * p) * 1536 + d];
    __syncthreads();
    bf16* dst = vT + (long)z * 32768 + pos0;
    int c = tid & 63, dr = tid >> 6;
#pragma unroll
    for (int p = 0; p < 16; p++)
        dst[(long)(dr + 4 * p) * 512 + c] = T[c][dr + 4 * p];
}

// ---------------- MFMA bf16 GEMM: C = A @ B^T, (WM*64)x(WN*64) tile, BK=32, WM*WN==4 ----------------
// flags: 1 = skip tiles with bx>by (triangular), 2 = Kend = min(K, m0+TM) (causal A).
// C2 (optional): bf16 dual-write into padded hbp layout (requires flat M, ldc==512):
//   C2[addr + ((mrow>>9)+1)*1024] == hbp row bl+2b+2.
template<int WM, int WN>
__global__ __launch_bounds__(256) void mm_bt(
    const bf16* __restrict__ A, int lda, long sAo, long sAi,
    const bf16* __restrict__ B, int ldb, long sBo, long sBi,
    float* __restrict__ Cf, bf16* __restrict__ Cb, int ldc, long sCo, long sCi,
    int K, int zdiv, int Nvalid, int flags,
    const float* __restrict__ bias, const float* __restrict__ Res,
    bf16* __restrict__ C2, int relu, float scale)
{
    if ((flags & 1) && blockIdx.x > blockIdx.y) return;
    int z = blockIdx.z;
    int zb = z / zdiv, zr = z - zb * zdiv;
    const bf16* Ap = A + zb * sAo + zr * sAi;
    const bf16* Bp = B + zb * sBo + zr * sBi;
    long cbase = zb * sCo + zr * sCi;
    int m0 = blockIdx.y * (WM * 64), n0 = blockIdx.x * (WN * 64);
    __shared__ __align__(16) bf16 As[WM * 64 * 32];
    __shared__ __align__(16) bf16 Bs[WN * 64 * 32];
    int tid = threadIdx.x, wave = tid >> 6, lane = tid & 63;
    int wm = wave / WN, wn = wave % WN;
    int lr = lane >> 2, lk = (lane & 3) * 8;
    int fm = lane & 15, fq = lane >> 4;
    bool nact = (n0 + wn * 64) < Nvalid;
    f32x4 acc[4][4] = {};
    int Kend = (flags & 2) ? ((K < m0 + WM * 64) ? K : (m0 + WM * 64)) : K;
    const bf16* gA[WM]; const bf16* gB[WN];
    bf16* lA[WM]; bf16* lB[WN];
#pragma unroll
    for (int i = 0; i < WM; i++) {
        gA[i] = Ap + (long)(m0 + wave * 16 + 64 * i + lr) * lda + lk;
        lA[i] = As + (wave * 16 + 64 * i) * 32;
    }
#pragma unroll
    for (int i = 0; i < WN; i++) {
        gB[i] = Bp + (long)(n0 + wave * 16 + 64 * i + lr) * ldb + lk;
        lB[i] = Bs + (wave * 16 + 64 * i) * 32;
    }

    for (int k0 = 0; k0 < Kend; k0 += 32) {
        __syncthreads();
#pragma unroll
        for (int i = 0; i < WM; i++)
            __builtin_amdgcn_global_load_lds((const AS1 void*)(gA[i] + k0), (AS3 void*)lA[i], 16, 0, 0);
#pragma unroll
        for (int i = 0; i < WN; i++)
            __builtin_amdgcn_global_load_lds((const AS1 void*)(gB[i] + k0), (AS3 void*)lB[i], 16, 0, 0);
        __syncthreads();
        if (nact) {
            bf16x8 af[4], bfr[4];
#pragma unroll
            for (int t = 0; t < 4; t++) {
                af[t]  = *(const bf16x8*)(As + (wm * 64 + t * 16 + fm) * 32 + fq * 8);
                bfr[t] = *(const bf16x8*)(Bs + (wn * 64 + t * 16 + fm) * 32 + fq * 8);
            }
#pragma unroll
            for (int i = 0; i < 4; i++)
#pragma unroll
                for (int j = 0; j < 4; j++)
                    acc[i][j] = __builtin_amdgcn_mfma_f32_16x16x32_bf16(af[i], bfr[j], acc[i][j], 0, 0, 0);
        }
    }

    if (!nact) return;
#pragma unroll
    for (int i = 0; i < 4; i++) {
        int mrow = m0 + wm * 64 + i * 16 + fq * 4;
#pragma unroll
        for (int j = 0; j < 4; j++) {
            int n = n0 + wn * 64 + j * 16 + fm;
            if (n < Nvalid) {
                float bs = bias ? bias[n] : 0.f;
#pragma unroll
                for (int r = 0; r < 4; r++) {
                    float c = acc[i][j][r] * scale + bs;
                    if (relu) c = fmaxf(c, 0.f);
                    long addr = cbase + (long)(mrow + r) * ldc + n;
                    if (Res) c += Res[addr];
                    if (Cf) Cf[addr] = c;
                    else    Cb[addr] = __float2bfloat16(c);
                    if (C2) C2[addr + (long)(((mrow + r) >> 9) + 1) * 1024] = __float2bfloat16(c);
                }
            }
        }
    }
}

// ---------------- top-k(256) threshold (exact radix select) + softmax; one wave per row ----------
__global__ __launch_bounds__(256) void topk_softmax(float* __restrict__ sc)
{
    int wave = threadIdx.x >> 6, lane = threadIdx.x & 63;
    int row = blockIdx.x * 4 + wave;   // z*512 + q
    int q = row & 511, z = row >> 9;
    float* s = sc + (long)z * 262144 + (long)q * 512;
    __shared__ int hist[4][256];
    int* H = hist[wave];
    float v[8]; unsigned key[8]; bool val[8];
#pragma unroll
    for (int p = 0; p < 8; p++) {
        int c = lane + 64 * p;
        val[p] = (c <= q);
        v[p] = val[p] ? s[c] : NEG;
        unsigned u = __float_as_uint(v[p]);
        key[p] = u ^ (unsigned)(((int)u >> 31) | 0x80000000);
    }
    // exact 256th-largest key among 512 entries (NEG fillers -> keep-all for q<256 rows)
    unsigned prefix = 0u, pmask = 0u; int kneed = 256;
#pragma unroll
    for (int shift = 24; shift >= 0; shift -= 8) {
#pragma unroll
        for (int i = 0; i < 4; i++) H[lane * 4 + i] = 0;
        __syncthreads();
#pragma unroll
        for (int p = 0; p < 8; p++)
            if (val[p] && (key[p] & pmask) == prefix)
                atomicAdd(&H[(key[p] >> shift) & 255], 1);
        __syncthreads();
        int b4 = lane * 4;
        int s0 = H[b4], s1 = H[b4 + 1], s2 = H[b4 + 2], s3 = H[b4 + 3];
        int tot = s0 + s1 + s2 + s3, run = tot;
#pragma unroll
        for (int off = 1; off < 64; off <<= 1) {
            int o = __shfl_down(run, off);
            if (lane + off < 64) run += o;
        }
        int above = run - tot;            // count in bins strictly above this lane's 4
        unsigned pack = 0u;
        if (above < kneed && kneed <= above + tot) {
            int c3 = above + s3, c2 = c3 + s2, c1 = c2 + s1;
            int dsel, rem;
            if (kneed <= c3)      { dsel = 3; rem = kneed - above; }
            else if (kneed <= c2) { dsel = 2; rem = kneed - c3; }
            else if (kneed <= c1) { dsel = 1; rem = kneed - c2; }
            else                  { dsel = 0; rem = kneed - c1; }
            pack = ((unsigned)(b4 + dsel) << 10) | (unsigned)rem;
        }
#pragma unroll
        for (int off = 1; off < 64; off <<= 1) pack |= __shfl_xor(pack, off);
        prefix |= (pack >> 10) << shift;
        kneed = (int)(pack & 1023u);
        pmask |= (0xFFu << shift);
        __syncthreads();
    }
    unsigned Tkey = prefix;
    float m = NEG;
#pragma unroll
    for (int p = 0; p < 8; p++) m = fmaxf(m, v[p]);
#pragma unroll
    for (int off = 1; off < 64; off <<= 1) m = fmaxf(m, __shfl_xor(m, off));
    float e[8]; float ssum = 0.f;
#pragma unroll
    for (int p = 0; p < 8; p++) {
        bool kp = val[p] && (key[p] >= Tkey);
        e[p] = kp ? expf(v[p] - m) : 0.f;
        ssum += e[p];
    }
#pragma unroll
    for (int off = 1; off < 64; off <<= 1) ssum += __shfl_xor(ssum, off);
    float inv = 1.f / ssum;
    bf16* sb = (bf16*)s;                  // in-place bf16 probs, row stride 1024 bf16
#pragma unroll
    for (int p = 0; p < 8; p++) sb[lane + 64 * p] = __float2bfloat16(e[p] * inv);
}

extern "C" void kernel_launch(void* const* d_in, const int* in_sizes, int n_in,
                              void* d_out, int out_size, void* d_ws, size_t ws_size,
                              hipStream_t stream)
{
    const float* x         = (const float*)d_in[0];
    const float* tf        = (const float*)d_in[1];
    const float* in_w      = (const float*)d_in[2];
    const float* in_b      = (const float*)d_in[3];
    const float* pos_emb   = (const float*)d_in[4];
    const float* temp_w    = (const float*)d_in[5];
    const float* temp_b    = (const float*)d_in[6];
    const float* pos_scale = (const float*)d_in[7];
    const float* temp_scale= (const float*)d_in[8];
    const float* conv_w    = (const float*)d_in[9];
    const float* conv_b    = (const float*)d_in[10];
    const float* qw        = (const float*)d_in[11];
    const float* qb        = (const float*)d_in[12];
    const float* kw        = (const float*)d_in[13];
    const float* kb        = (const float*)d_in[14];
    const float* vw        = (const float*)d_in[15];
    const float* vb        = (const float*)d_in[16];
    const float* ow        = (const float*)d_in[17];
    const float* ob        = (const float*)d_in[18];
    const float* f1w       = (const float*)d_in[19];
    const float* f1b       = (const float*)d_in[20];
    const float* f2w       = (const float*)d_in[21];
    const float* f2b       = (const float*)d_in[22];
    const float* n1s       = (const float*)d_in[23];
    const float* n1b       = (const float*)d_in[24];
    const float* n2s       = (const float*)d_in[25];
    const float* n2b       = (const float*)d_in[26];

    if (ws_size < (size_t)B_END) return;

    char* wsb = (char*)d_ws;
    float* h    = (float*)(wsb + B_H);
    float* tmp  = (float*)(wsb + B_TMP);
    float* scb  = (float*)(wsb + B_SC);
    float* extras = (float*)(wsb + B_SC);          // reuses scores region before attention
    bf16*  xb   = (bf16*)(wsb + B_HB);
    bf16*  inwT = (bf16*)(wsb + B_HB + 1048576);
    bf16*  hbp  = (bf16*)(wsb + B_HPAD);           // [8][514][512] padded bf16 h
    bf16*  qkv  = (bf16*)(wsb + B_QKV);
    bf16*  vT   = (bf16*)(wsb + B_VT);
    bf16*  ao   = (bf16*)(wsb + B_AO);
    bf16*  mid  = (bf16*)(wsb + B_MID);
    bf16*  wC   = (bf16*)(wsb + B_WC);
    bf16*  wQKV = (bf16*)(wsb + B_WQKV);
    bf16*  wO   = (bf16*)(wsb + B_WO);
    bf16*  wF1  = (bf16*)(wsb + B_WF1);
    bf16*  wF2  = (bf16*)(wsb + B_WF2);
    float* bqkv = (float*)(wsb + B_BIAS);

    // ---- weight prep ----
    convw_bf<<<(4 * 512 * 1536) / 256, 256, 0, stream>>>(conv_w, wC);
    {
        dim3 gw(16, 2, 1);
        wtrans<<<gw, 256, 0, stream>>>(in_w, inwT,         512, 64, 0L, 0L);
        dim3 g(16, 16, 4);
        wtrans<<<g, 256, 0, stream>>>(qw, wQKV,            512, 512, 262144L, 786432L);
        wtrans<<<g, 256, 0, stream>>>(kw, wQKV + 262144,   512, 512, 262144L, 786432L);
        wtrans<<<g, 256, 0, stream>>>(vw, wQKV + 524288,   512, 512, 262144L, 786432L);
        wtrans<<<g, 256, 0, stream>>>(ow, wO,              512, 512, 262144L, 262144L);
        dim3 g1(64, 16, 4);
        wtrans<<<g1, 256, 0, stream>>>(f1w, wF1,          2048, 512, 1048576L, 1048576L);
        dim3 g2(16, 64, 4);
        wtrans<<<g2, 256, 0, stream>>>(f2w, wF2,           512, 2048, 1048576L, 1048576L);
    }
    biascat<<<24, 256, 0, stream>>>(qb, kb, vb, bqkv);
    zpad<<<32, 256, 0, stream>>>(hbp);
    prep_embed<<<4096, 256, 0, stream>>>(x, tf, in_b, pos_emb, temp_w, temp_b,
                                         pos_scale, temp_scale, xb, extras);
    // embed = x @ in_w + extras  -> h (f32) + hbp (bf16, padded)
    {
        dim3 g(4, 32, 1);
        mm_bt<2, 2><<<g, 256, 0, stream>>>(xb, 64, 0L, 0L,
                                           inwT, 64, 0L, 0L,
                                           h, nullptr, 512, 0L, 0L,
                                           64, 1, 512, 0,
                                           nullptr, extras, hbp, 0, 1.f);
    }

    for (int l = 0; l < El; l++) {
        // causal conv as GEMM over padded hbp window, K = 3*512, z-batched
        {
            dim3 g(4, 4, 8);
            mm_bt<2, 2><<<g, 256, 0, stream>>>(hbp, 512, 263168L, 0L,
                                               wC + (long)l * 786432, 1536, 0L, 0L,
                                               tmp, nullptr, 512, 262144L, 0L,
                                               1536, 1, 512, 0,
                                               conv_b + (long)l * 512, nullptr, nullptr, 0, 1.f);
        }
        ln_kernel<<<Bsz * Lq, 256, 0, stream>>>(h, hbp, tmp, n1s + (long)l * 512, n1b + (long)l * 512);

        // fused QKV (z-batched over batch): [512,512] @ [512,1536] per b
        {
            dim3 g(12, 4, 8);
            mm_bt<2, 2><<<g, 256, 0, stream>>>(hbp + 1024, 512, 263168L, 0L,
                                               wQKV + (long)l * 786432, 512, 0L, 0L,
                                               nullptr, qkv, 1536, 786432L, 0L,
                                               512, 1, 1536, 0,
                                               bqkv + (long)l * 1536, nullptr, nullptr, 0, 1.f);
        }

        // scores = 0.125 * q @ k^T (lower-triangle tiles) -> f32 scb
        {
            dim3 g(4, 4, 64);
            mm_bt<2, 2><<<g, 256, 0, stream>>>(qkv, 1536, 786432L, 64L,
                                               qkv + 512, 1536, 786432L, 64L,
                                               scb, nullptr, 512, 2097152L, 262144L,
                                               64, 8, 512, 1,
                                               nullptr, nullptr, nullptr, 0, 0.125f);
        }
        topk_softmax<<<Bsz * Hh * Lq / 4, 256, 0, stream>>>(scb);
        {
            dim3 gv(8, 64, 1);
            vtrans<<<gv, 256, 0, stream>>>(qkv, vT);
        }
        // attn @ v : 256x64 tile (all waves active), causal K limit
        {
            dim3 g(1, 2, 64);
            mm_bt<4, 1><<<g, 256, 0, stream>>>((const bf16*)scb, 1024, 4194304L, 524288L,
                                               vT, 512, 262144L, 32768L,
                                               nullptr, ao, 512, 262144L, 64L,
                                               512, 8, 64, 2,
                                               nullptr, nullptr, nullptr, 0, 1.f);
        }
        // out proj
        {
            dim3 g(4, 32, 1);
            mm_bt<2, 2><<<g, 256, 0, stream>>>(ao, 512, 0L, 0L,
                                               wO + (long)l * 262144, 512, 0L, 0L,
                                               tmp, nullptr, 512, 0L, 0L,
                                               512, 1, 512, 0,
                                               ob + (long)l * 512, nullptr, nullptr, 0, 1.f);
        }
        ln_kernel<<<Bsz * Lq, 256, 0, stream>>>(h, hbp, tmp, n2s + (long)l * 512, n2b + (long)l * 512);

        // FFN1 (relu) -> bf16 mid, z-batched
        {
            dim3 g(16, 4, 8);
            mm_bt<2, 2><<<g, 256, 0, stream>>>(hbp + 1024, 512, 263168L, 0L,
                                               wF1 + (long)l * 1048576, 512, 0L, 0L,
                                               nullptr, mid, 2048, 1048576L, 0L,
                                               512, 1, 2048, 0,
                                               f1b + (long)l * 2048, nullptr, nullptr, 1, 1.f);
        }
        // FFN2 + residual -> f32 h + bf16 hbp (padded)
        {
            dim3 g(4, 32, 1);
            mm_bt<2, 2><<<g, 256, 0, stream>>>(mid, 2048, 0L, 0L,
                                               wF2 + (long)l * 1048576, 2048, 0L, 0L,
                                               h, nullptr, 512, 0L, 0L,
                                               2048, 1, 512, 0,
                                               f2b + (long)l * 512, h, hbp, 0, 1.f);
        }
    }

    hipMemcpyAsync(d_out, h, (size_t)out_size * sizeof(float), hipMemcpyDeviceToDevice, stream);
}

// Round 6
// 1407.485 us; speedup vs baseline: 2.9889x; 1.0005x over previous
//
#include <hip/hip_runtime.h>
#include <hip/hip_bf16.h>
#include <math.h>

#define Bsz 8
#define Lq  512
#define Dm  512
#define Hh  8
#define El  4
#define DFF 2048
#define NEG (-3.0e38f)

typedef __hip_bfloat16 bf16;
typedef __attribute__((ext_vector_type(8))) short bf16x8;
typedef __attribute__((ext_vector_type(4))) float f32x4;

// ---------------- workspace layout (BYTE offsets) ----------------
#define B_H     0L            // f32 h                4096x512        8 MB
#define B_TMP   8388608L      // f32 tmp              4096x512        8 MB
#define B_SC    16777216L     // f32 scores 64x512x512 (bf16 probs in place); extras pre-attn  64 MB
#define B_HB    83886080L     // bf16 xb (512KB) + bf16 in_wT (64KB)
#define B_HPAD  88080384L     // bf16 hbp padded h    8x514x512       4.21 MB
#define B_QKV   92291072L     // bf16 qkv             4096x1536      12 MB
#define B_VT    104873984L    // bf16 vT              64x64x512       4 MB
#define B_AO    109068288L    // bf16 attn out        4096x512        4 MB
#define B_MID   113262592L    // bf16 ffn mid         4096x2048      16 MB
#define B_WC    130039808L    // bf16 conv wT         4x512x1536      6 MB
#define B_WQKV  136331264L    // bf16 qkv wT          4x1536x512      6 MB
#define B_WO    142622720L    // bf16 o wT            4x512x512       2 MB
#define B_WF1   144719872L    // bf16 f1 wT           4x2048x512      8 MB
#define B_WF2   153108480L    // bf16 f2 wT           4x512x2048      8 MB
#define B_BIAS  161497088L    // f32 qkv bias cat     4x1536         24 KB
#define B_END   161521664L

// ---------------- zero the 2 pad rows per batch in hbp ----------------
__global__ __launch_bounds__(256) void zpad(bf16* __restrict__ hbp)
{
    int i = blockIdx.x * 256 + threadIdx.x;    // 8 batches x 2 rows x 512
    if (i < 8192) {
        int b = i >> 10, r = i & 1023;
        hbp[(long)b * 263168 + r] = __float2bfloat16(0.f);
    }
}

// ---------------- embed prep: cast x->bf16, extras = in_b + ps*pos + ts*(tf@tw+tb) ----------------
__global__ __launch_bounds__(256) void prep_embed(
    const float* __restrict__ x, const float* __restrict__ tf,
    const float* __restrict__ in_b, const float* __restrict__ pos_emb,
    const float* __restrict__ temp_w, const float* __restrict__ temp_b,
    const float* __restrict__ pos_scale, const float* __restrict__ temp_scale,
    bf16* __restrict__ xb, float* __restrict__ extras)
{
    int bl = blockIdx.x, l = bl & 511, tid = threadIdx.x;
    if (tid < 64) xb[(long)bl * 64 + tid] = __float2bfloat16(x[(long)bl * 64 + tid]);
    float ps = pos_scale[0], ts = temp_scale[0];
    float t0 = tf[(long)bl * 2], t1 = tf[(long)bl * 2 + 1];
    for (int d = tid; d < 512; d += 256)
        extras[(long)bl * 512 + d] = in_b[d] + ps * pos_emb[(long)l * 512 + d]
                                   + ts * (t0 * temp_w[d] + t1 * temp_w[512 + d] + temp_b[d]);
}

// ---------------- conv weight: [dout][din][kk] -> bf16 BT[dout][kk*512+din] ----------------
__global__ __launch_bounds__(256) void convw_bf(const float* __restrict__ cw, bf16* __restrict__ out)
{
    long i = (long)blockIdx.x * 256 + threadIdx.x;
    const long total = 4L * 512 * 1536;
    if (i >= total) return;
    int din = (int)(i & 511);
    int kk  = (int)((i >> 9) % 3);
    long r  = i / 1536;
    int dout = (int)(r & 511);
    int z    = (int)(r >> 9);
    out[i] = __float2bfloat16(cw[(((long)z * 512 + dout) * 512 + din) * 3 + kk]);
}

// ---------------- generic f32 (K,N) -> bf16 (N,K) transpose, z-batched ----------------
__global__ __launch_bounds__(256) void wtrans(
    const float* __restrict__ in, bf16* __restrict__ out,
    int N, int Kd, long sIn, long sOut)
{
    int z = blockIdx.z;
    int n0 = blockIdx.x * 32, k0 = blockIdx.y * 32;
    int tid = threadIdx.x;
    int tx = tid & 31, ty = tid >> 5;   // ty 0..7
    __shared__ float t[32][33];
#pragma unroll
    for (int p = 0; p < 4; p++)
        t[ty + 8 * p][tx] = in[z * sIn + (long)(k0 + ty + 8 * p) * N + n0 + tx];
    __syncthreads();
#pragma unroll
    for (int p = 0; p < 4; p++)
        out[z * sOut + (long)(n0 + ty + 8 * p) * Kd + k0 + tx] = __float2bfloat16(t[tx][ty + 8 * p]);
}

// ---------------- concat q/k/v biases ----------------
__global__ __launch_bounds__(256) void biascat(
    const float* __restrict__ qb, const float* __restrict__ kb,
    const float* __restrict__ vb, float* __restrict__ out)
{
    int i = blockIdx.x * 256 + threadIdx.x;
    if (i >= 4 * 1536) return;
    int l = i / 1536, j = i - l * 1536;
    float v = (j < 512) ? qb[l * 512 + j] : (j < 1024) ? kb[l * 512 + j - 512] : vb[l * 512 + j - 1024];
    out[i] = v;
}

// ---------------- residual + LayerNorm -> f32 h + bf16 copy into padded hbp ----------------
__global__ __launch_bounds__(256) void ln_kernel(
    float* __restrict__ h, bf16* __restrict__ hbp, const float* __restrict__ r,
    const float* __restrict__ sc, const float* __restrict__ bi)
{
    long base = (long)blockIdx.x * Dm;
    int b = blockIdx.x >> 9;
    long hbase = base + (long)(b + 1) * 1024;   // hbp row = bl + 2*b + 2
    int tid = threadIdx.x;
    float v0 = h[base + tid] + r[base + tid];
    float v1 = h[base + tid + 256] + r[base + tid + 256];
    __shared__ float red[16];
    int lane = tid & 63, wid = tid >> 6;
    float s = v0 + v1;
    for (int off = 32; off; off >>= 1) s += __shfl_down(s, off);
    if (!lane) red[wid] = s;
    __syncthreads();
    float mean = (red[0] + red[1] + red[2] + red[3]) * (1.f / 512.f);
    float d0 = v0 - mean, d1 = v1 - mean;
    float vs = d0 * d0 + d1 * d1;
    for (int off = 32; off; off >>= 1) vs += __shfl_down(vs, off);
    if (!lane) red[4 + wid] = vs;
    __syncthreads();
    float var = (red[4] + red[5] + red[6] + red[7]) * (1.f / 512.f);
    float inv = rsqrtf(var + 1e-5f);
    float o0 = d0 * inv * sc[tid] + bi[tid];
    float o1 = d1 * inv * sc[tid + 256] + bi[tid + 256];
    h[base + tid]         = o0;
    h[base + tid + 256]   = o1;
    hbp[hbase + tid]       = __float2bfloat16(o0);
    hbp[hbase + tid + 256] = __float2bfloat16(o1);
}

// ---------------- v transpose: qkv v-part [pos][d] -> vT [z][d][pos] bf16 ----------------
__global__ __launch_bounds__(256) void vtrans(const bf16* __restrict__ qkv, bf16* __restrict__ vT)
{
    int z = blockIdx.y, b = z >> 3, hh = z & 7;
    int pos0 = blockIdx.x * 64;
    __shared__ bf16 T[64][65];
    int tid = threadIdx.x;
    int d = tid & 63, pr = tid >> 6;
    const bf16* src = qkv + ((long)(b * 512 + pos0)) * 1536 + 1024 + hh * 64;
#pragma unroll
    for (int p = 0; p < 16; p++)
        T[pr + 4 * p][d] = src[(long)(pr + 4 * p) * 1536 + d];
    __syncthreads();
    bf16* dst = vT + (long)z * 32768 + pos0;
    int c = tid & 63, dr = tid >> 6;
#pragma unroll
    for (int p = 0; p < 16; p++)
        dst[(long)(dr + 4 * p) * 512 + c] = T[c][dr + 4 * p];
}

// ---------------- MFMA bf16 GEMM: one wave per 64x64 tile, direct global->VGPR, no LDS ------------
// A: [M][K] bf16 (lda), B: [N][K] bf16 (ldb). z: zb=z/zdiv (outer), zr=z%zdiv (inner).
// flags: 1 = skip tiles with bx>by (triangular), 2 = Kend = min(K, m0+64) (causal A).
// Register double-buffer: loads for k+1 issue before the 16 MFMAs of k (no barriers at all).
__global__ __launch_bounds__(64) void mm_bt(
    const bf16* __restrict__ A, int lda, long sAo, long sAi,
    const bf16* __restrict__ B, int ldb, long sBo, long sBi,
    float* __restrict__ Cf, bf16* __restrict__ Cb, int ldc, long sCo, long sCi,
    int K, int zdiv, int Nvalid, int flags,
    const float* __restrict__ bias, const float* __restrict__ Res,
    bf16* __restrict__ C2, int relu, float scale)
{
    if ((flags & 1) && blockIdx.x > blockIdx.y) return;
    int z = blockIdx.z;
    int zb = z / zdiv, zr = z - zb * zdiv;
    const bf16* Ap = A + zb * sAo + zr * sAi;
    const bf16* Bp = B + zb * sBo + zr * sBi;
    long cbase = zb * sCo + zr * sCi;
    int m0 = blockIdx.y * 64, n0 = blockIdx.x * 64;
    int lane = threadIdx.x;
    int fm = lane & 15, fq = lane >> 4;
    const bf16* ap[4]; const bf16* bp[4];
#pragma unroll
    for (int t = 0; t < 4; t++) {
        ap[t] = Ap + (long)(m0 + t * 16 + fm) * lda + fq * 8;
        bp[t] = Bp + (long)(n0 + t * 16 + fm) * ldb + fq * 8;
    }
    int Kend = (flags & 2) ? ((K < m0 + 64) ? K : (m0 + 64)) : K;
    f32x4 acc[4][4] = {};
    bf16x8 a0[4], b0[4], a1[4], b1[4];
#pragma unroll
    for (int t = 0; t < 4; t++) { a0[t] = *(const bf16x8*)(ap[t]); b0[t] = *(const bf16x8*)(bp[t]); }
    for (int k0 = 0; k0 < Kend; k0 += 32) {
        if (k0 + 32 < Kend) {
#pragma unroll
            for (int t = 0; t < 4; t++) {
                a1[t] = *(const bf16x8*)(ap[t] + k0 + 32);
                b1[t] = *(const bf16x8*)(bp[t] + k0 + 32);
            }
        }
#pragma unroll
        for (int i = 0; i < 4; i++)
#pragma unroll
            for (int j = 0; j < 4; j++)
                acc[i][j] = __builtin_amdgcn_mfma_f32_16x16x32_bf16(a0[i], b0[j], acc[i][j], 0, 0, 0);
#pragma unroll
        for (int t = 0; t < 4; t++) { a0[t] = a1[t]; b0[t] = b1[t]; }
    }

#pragma unroll
    for (int i = 0; i < 4; i++) {
        int mrow = m0 + i * 16 + fq * 4;
#pragma unroll
        for (int j = 0; j < 4; j++) {
            int n = n0 + j * 16 + fm;
            if (n < Nvalid) {
                float bs = bias ? bias[n] : 0.f;
#pragma unroll
                for (int r = 0; r < 4; r++) {
                    float c = acc[i][j][r] * scale + bs;
                    if (relu) c = fmaxf(c, 0.f);
                    long addr = cbase + (long)(mrow + r) * ldc + n;
                    if (Res) c += Res[addr];
                    if (Cf) Cf[addr] = c;
                    else    Cb[addr] = __float2bfloat16(c);
                    if (C2) C2[addr + (long)(((mrow + r) >> 9) + 1) * 1024] = __float2bfloat16(c);
                }
            }
        }
    }
}

// ---------------- top-k(256) threshold (exact radix select) + softmax; one wave per row ----------
__global__ __launch_bounds__(256) void topk_softmax(float* __restrict__ sc)
{
    int wave = threadIdx.x >> 6, lane = threadIdx.x & 63;
    int row = blockIdx.x * 4 + wave;   // z*512 + q
    int q = row & 511, z = row >> 9;
    float* s = sc + (long)z * 262144 + (long)q * 512;
    __shared__ int hist[4][256];
    int* H = hist[wave];
    float v[8]; unsigned key[8]; bool val[8];
#pragma unroll
    for (int p = 0; p < 8; p++) {
        int c = lane + 64 * p;
        val[p] = (c <= q);
        v[p] = val[p] ? s[c] : NEG;
        unsigned u = __float_as_uint(v[p]);
        key[p] = u ^ (unsigned)(((int)u >> 31) | 0x80000000);
    }
    unsigned prefix = 0u, pmask = 0u; int kneed = 256;
#pragma unroll
    for (int shift = 24; shift >= 0; shift -= 8) {
#pragma unroll
        for (int i = 0; i < 4; i++) H[lane * 4 + i] = 0;
        __syncthreads();
#pragma unroll
        for (int p = 0; p < 8; p++)
            if (val[p] && (key[p] & pmask) == prefix)
                atomicAdd(&H[(key[p] >> shift) & 255], 1);
        __syncthreads();
        int b4 = lane * 4;
        int s0 = H[b4], s1 = H[b4 + 1], s2 = H[b4 + 2], s3 = H[b4 + 3];
        int tot = s0 + s1 + s2 + s3, run = tot;
#pragma unroll
        for (int off = 1; off < 64; off <<= 1) {
            int o = __shfl_down(run, off);
            if (lane + off < 64) run += o;
        }
        int above = run - tot;
        unsigned pack = 0u;
        if (above < kneed && kneed <= above + tot) {
            int c3 = above + s3, c2 = c3 + s2, c1 = c2 + s1;
            int dsel, rem;
            if (kneed <= c3)      { dsel = 3; rem = kneed - above; }
            else if (kneed <= c2) { dsel = 2; rem = kneed - c3; }
            else if (kneed <= c1) { dsel = 1; rem = kneed - c2; }
            else                  { dsel = 0; rem = kneed - c1; }
            pack = ((unsigned)(b4 + dsel) << 10) | (unsigned)rem;
        }
#pragma unroll
        for (int off = 1; off < 64; off <<= 1) pack |= __shfl_xor(pack, off);
        prefix |= (pack >> 10) << shift;
        kneed = (int)(pack & 1023u);
        pmask |= (0xFFu << shift);
        __syncthreads();
    }
    unsigned Tkey = prefix;
    float m = NEG;
#pragma unroll
    for (int p = 0; p < 8; p++) m = fmaxf(m, v[p]);
#pragma unroll
    for (int off = 1; off < 64; off <<= 1) m = fmaxf(m, __shfl_xor(m, off));
    float e[8]; float ssum = 0.f;
#pragma unroll
    for (int p = 0; p < 8; p++) {
        bool kp = val[p] && (key[p] >= Tkey);
        e[p] = kp ? expf(v[p] - m) : 0.f;
        ssum += e[p];
    }
#pragma unroll
    for (int off = 1; off < 64; off <<= 1) ssum += __shfl_xor(ssum, off);
    float inv = 1.f / ssum;
    bf16* sb = (bf16*)s;                  // in-place bf16 probs, row stride 1024 bf16
#pragma unroll
    for (int p = 0; p < 8; p++) sb[lane + 64 * p] = __float2bfloat16(e[p] * inv);
}

extern "C" void kernel_launch(void* const* d_in, const int* in_sizes, int n_in,
                              void* d_out, int out_size, void* d_ws, size_t ws_size,
                              hipStream_t stream)
{
    const float* x         = (const float*)d_in[0];
    const float* tf        = (const float*)d_in[1];
    const float* in_w      = (const float*)d_in[2];
    const float* in_b      = (const float*)d_in[3];
    const float* pos_emb   = (const float*)d_in[4];
    const float* temp_w    = (const float*)d_in[5];
    const float* temp_b    = (const float*)d_in[6];
    const float* pos_scale = (const float*)d_in[7];
    const float* temp_scale= (const float*)d_in[8];
    const float* conv_w    = (const float*)d_in[9];
    const float* conv_b    = (const float*)d_in[10];
    const float* qw        = (const float*)d_in[11];
    const float* qb        = (const float*)d_in[12];
    const float* kw        = (const float*)d_in[13];
    const float* kb        = (const float*)d_in[14];
    const float* vw        = (const float*)d_in[15];
    const float* vb        = (const float*)d_in[16];
    const float* ow        = (const float*)d_in[17];
    const float* ob        = (const float*)d_in[18];
    const float* f1w       = (const float*)d_in[19];
    const float* f1b       = (const float*)d_in[20];
    const float* f2w       = (const float*)d_in[21];
    const float* f2b       = (const float*)d_in[22];
    const float* n1s       = (const float*)d_in[23];
    const float* n1b       = (const float*)d_in[24];
    const float* n2s       = (const float*)d_in[25];
    const float* n2b       = (const float*)d_in[26];

    if (ws_size < (size_t)B_END) return;

    char* wsb = (char*)d_ws;
    float* h    = (float*)(wsb + B_H);
    float* tmp  = (float*)(wsb + B_TMP);
    float* scb  = (float*)(wsb + B_SC);
    float* extras = (float*)(wsb + B_SC);          // reuses scores region before attention
    bf16*  xb   = (bf16*)(wsb + B_HB);
    bf16*  inwT = (bf16*)(wsb + B_HB + 1048576);
    bf16*  hbp  = (bf16*)(wsb + B_HPAD);           // [8][514][512] padded bf16 h
    bf16*  qkv  = (bf16*)(wsb + B_QKV);
    bf16*  vT   = (bf16*)(wsb + B_VT);
    bf16*  ao   = (bf16*)(wsb + B_AO);
    bf16*  mid  = (bf16*)(wsb + B_MID);
    bf16*  wC   = (bf16*)(wsb + B_WC);
    bf16*  wQKV = (bf16*)(wsb + B_WQKV);
    bf16*  wO   = (bf16*)(wsb + B_WO);
    bf16*  wF1  = (bf16*)(wsb + B_WF1);
    bf16*  wF2  = (bf16*)(wsb + B_WF2);
    float* bqkv = (float*)(wsb + B_BIAS);

    // ---- weight prep ----
    convw_bf<<<(4 * 512 * 1536) / 256, 256, 0, stream>>>(conv_w, wC);
    {
        dim3 gw(16, 2, 1);
        wtrans<<<gw, 256, 0, stream>>>(in_w, inwT,         512, 64, 0L, 0L);
        dim3 g(16, 16, 4);
        wtrans<<<g, 256, 0, stream>>>(qw, wQKV,            512, 512, 262144L, 786432L);
        wtrans<<<g, 256, 0, stream>>>(kw, wQKV + 262144,   512, 512, 262144L, 786432L);
        wtrans<<<g, 256, 0, stream>>>(vw, wQKV + 524288,   512, 512, 262144L, 786432L);
        wtrans<<<g, 256, 0, stream>>>(ow, wO,              512, 512, 262144L, 262144L);
        dim3 g1(64, 16, 4);
        wtrans<<<g1, 256, 0, stream>>>(f1w, wF1,          2048, 512, 1048576L, 1048576L);
        dim3 g2(16, 64, 4);
        wtrans<<<g2, 256, 0, stream>>>(f2w, wF2,           512, 2048, 1048576L, 1048576L);
    }
    biascat<<<24, 256, 0, stream>>>(qb, kb, vb, bqkv);
    zpad<<<32, 256, 0, stream>>>(hbp);
    prep_embed<<<4096, 256, 0, stream>>>(x, tf, in_b, pos_emb, temp_w, temp_b,
                                         pos_scale, temp_scale, xb, extras);
    // embed = x @ in_w + extras  -> h (f32) + hbp (bf16, padded)
    {
        dim3 g(8, 64, 1);
        mm_bt<<<g, 64, 0, stream>>>(xb, 64, 0L, 0L,
                                    inwT, 64, 0L, 0L,
                                    h, nullptr, 512, 0L, 0L,
                                    64, 1, 512, 0,
                                    nullptr, extras, hbp, 0, 1.f);
    }

    for (int l = 0; l < El; l++) {
        // causal conv as GEMM over padded hbp window, K = 3*512, z-batched
        {
            dim3 g(8, 8, 8);
            mm_bt<<<g, 64, 0, stream>>>(hbp, 512, 263168L, 0L,
                                        wC + (long)l * 786432, 1536, 0L, 0L,
                                        tmp, nullptr, 512, 262144L, 0L,
                                        1536, 1, 512, 0,
                                        conv_b + (long)l * 512, nullptr, nullptr, 0, 1.f);
        }
        ln_kernel<<<Bsz * Lq, 256, 0, stream>>>(h, hbp, tmp, n1s + (long)l * 512, n1b + (long)l * 512);

        // fused QKV (z-batched over batch): [512,512] @ [512,1536] per b
        {
            dim3 g(24, 8, 8);
            mm_bt<<<g, 64, 0, stream>>>(hbp + 1024, 512, 263168L, 0L,
                                        wQKV + (long)l * 786432, 512, 0L, 0L,
                                        nullptr, qkv, 1536, 786432L, 0L,
                                        512, 1, 1536, 0,
                                        bqkv + (long)l * 1536, nullptr, nullptr, 0, 1.f);
        }

        // scores = 0.125 * q @ k^T (lower-triangle tiles) -> f32 scb
        {
            dim3 g(8, 8, 64);
            mm_bt<<<g, 64, 0, stream>>>(qkv, 1536, 786432L, 64L,
                                        qkv + 512, 1536, 786432L, 64L,
                                        scb, nullptr, 512, 2097152L, 262144L,
                                        64, 8, 512, 1,
                                        nullptr, nullptr, nullptr, 0, 0.125f);
        }
        topk_softmax<<<Bsz * Hh * Lq / 4, 256, 0, stream>>>(scb);
        {
            dim3 gv(8, 64, 1);
            vtrans<<<gv, 256, 0, stream>>>(qkv, vT);
        }
        // attn @ v : causal K limit, Nvalid=64
        {
            dim3 g(1, 8, 64);
            mm_bt<<<g, 64, 0, stream>>>((const bf16*)scb, 1024, 4194304L, 524288L,
                                        vT, 512, 262144L, 32768L,
                                        nullptr, ao, 512, 262144L, 64L,
                                        512, 8, 64, 2,
                                        nullptr, nullptr, nullptr, 0, 1.f);
        }
        // out proj
        {
            dim3 g(8, 64, 1);
            mm_bt<<<g, 64, 0, stream>>>(ao, 512, 0L, 0L,
                                        wO + (long)l * 262144, 512, 0L, 0L,
                                        tmp, nullptr, 512, 0L, 0L,
                                        512, 1, 512, 0,
                                        ob + (long)l * 512, nullptr, nullptr, 0, 1.f);
        }
        ln_kernel<<<Bsz * Lq, 256, 0, stream>>>(h, hbp, tmp, n2s + (long)l * 512, n2b + (long)l * 512);

        // FFN1 (relu) -> bf16 mid, z-batched
        {
            dim3 g(32, 8, 8);
            mm_bt<<<g, 64, 0, stream>>>(hbp + 1024, 512, 263168L, 0L,
                                        wF1 + (long)l * 1048576, 512, 0L, 0L,
                                        nullptr, mid, 2048, 1048576L, 0L,
                                        512, 1, 2048, 0,
                                        f1b + (long)l * 2048, nullptr, nullptr, 1, 1.f);
        }
        // FFN2 + residual -> f32 h + bf16 hbp (padded)
        {
            dim3 g(8, 64, 1);
            mm_bt<<<g, 64, 0, stream>>>(mid, 2048, 0L, 0L,
                                        wF2 + (long)l * 1048576, 2048, 0L, 0L,
                                        h, nullptr, 512, 0L, 0L,
                                        2048, 1, 512, 0,
                                        f2b + (long)l * 512, h, hbp, 0, 1.f);
        }
    }

    hipMemcpyAsync(d_out, h, (size_t)out_size * sizeof(float), hipMemcpyDeviceToDevice, stream);
}

// Round 7
// 1282.749 us; speedup vs baseline: 3.2795x; 1.0972x over previous
//
#include <hip/hip_runtime.h>
#include <hip/hip_bf16.h>
#include <math.h>

#define Bsz 8
#define Lq  512
#define Dm  512
#define Hh  8
#define El  4
#define DFF 2048
#define NEG (-3.0e38f)

typedef __hip_bfloat16 bf16;
typedef __attribute__((ext_vector_type(8))) short bf16x8;
typedef __attribute__((ext_vector_type(4))) float f32x4;

#define AS1 __attribute__((address_space(1)))
#define AS3 __attribute__((address_space(3)))

// ---------------- workspace layout (BYTE offsets) ----------------
#define B_H     0L            // f32 h                4096x512        8 MB
#define B_TMP   8388608L      // f32 tmp              4096x512        8 MB
#define B_SC    16777216L     // f32 scores 64x512x512 (bf16 probs in place); extras pre-attn  64 MB
#define B_HB    83886080L     // bf16 xb (512KB) + bf16 in_wT (64KB)
#define B_HPAD  88080384L     // bf16 hbp padded h    8x514x512       4.21 MB
#define B_QKV   92291072L     // bf16 qkv             4096x1536      12 MB
#define B_VT    104873984L    // bf16 vT              64x64x512       4 MB
#define B_AO    109068288L    // bf16 attn out        4096x512        4 MB
#define B_MID   113262592L    // bf16 ffn mid         4096x2048      16 MB
#define B_WC    130039808L    // bf16 conv wT         4x512x1536      6 MB
#define B_WQKV  136331264L    // bf16 qkv wT          4x1536x512      6 MB
#define B_WO    142622720L    // bf16 o wT            4x512x512       2 MB
#define B_WF1   144719872L    // bf16 f1 wT           4x2048x512      8 MB
#define B_WF2   153108480L    // bf16 f2 wT           4x512x2048      8 MB
#define B_BIAS  161497088L    // f32 qkv bias cat     4x1536         24 KB
#define B_END   161521664L

// ---------------- zero the 2 pad rows per batch in hbp ----------------
__global__ __launch_bounds__(256) void zpad(bf16* __restrict__ hbp)
{
    int i = blockIdx.x * 256 + threadIdx.x;    // 8 batches x 2 rows x 512
    if (i < 8192) {
        int b = i >> 10, r = i & 1023;
        hbp[(long)b * 263168 + r] = __float2bfloat16(0.f);
    }
}

// ---------------- embed prep: cast x->bf16, extras = in_b + ps*pos + ts*(tf@tw+tb) ----------------
__global__ __launch_bounds__(256) void prep_embed(
    const float* __restrict__ x, const float* __restrict__ tf,
    const float* __restrict__ in_b, const float* __restrict__ pos_emb,
    const float* __restrict__ temp_w, const float* __restrict__ temp_b,
    const float* __restrict__ pos_scale, const float* __restrict__ temp_scale,
    bf16* __restrict__ xb, float* __restrict__ extras)
{
    int bl = blockIdx.x, l = bl & 511, tid = threadIdx.x;
    if (tid < 64) xb[(long)bl * 64 + tid] = __float2bfloat16(x[(long)bl * 64 + tid]);
    float ps = pos_scale[0], ts = temp_scale[0];
    float t0 = tf[(long)bl * 2], t1 = tf[(long)bl * 2 + 1];
    for (int d = tid; d < 512; d += 256)
        extras[(long)bl * 512 + d] = in_b[d] + ps * pos_emb[(long)l * 512 + d]
                                   + ts * (t0 * temp_w[d] + t1 * temp_w[512 + d] + temp_b[d]);
}

// ---------------- conv weight: [dout][din][kk] -> bf16 BT[dout][kk*512+din] ----------------
__global__ __launch_bounds__(256) void convw_bf(const float* __restrict__ cw, bf16* __restrict__ out)
{
    long i = (long)blockIdx.x * 256 + threadIdx.x;
    const long total = 4L * 512 * 1536;
    if (i >= total) return;
    int din = (int)(i & 511);
    int kk  = (int)((i >> 9) % 3);
    long r  = i / 1536;
    int dout = (int)(r & 511);
    int z    = (int)(r >> 9);
    out[i] = __float2bfloat16(cw[(((long)z * 512 + dout) * 512 + din) * 3 + kk]);
}

// ---------------- generic f32 (K,N) -> bf16 (N,K) transpose, z-batched ----------------
__global__ __launch_bounds__(256) void wtrans(
    const float* __restrict__ in, bf16* __restrict__ out,
    int N, int Kd, long sIn, long sOut)
{
    int z = blockIdx.z;
    int n0 = blockIdx.x * 32, k0 = blockIdx.y * 32;
    int tid = threadIdx.x;
    int tx = tid & 31, ty = tid >> 5;   // ty 0..7
    __shared__ float t[32][33];
#pragma unroll
    for (int p = 0; p < 4; p++)
        t[ty + 8 * p][tx] = in[z * sIn + (long)(k0 + ty + 8 * p) * N + n0 + tx];
    __syncthreads();
#pragma unroll
    for (int p = 0; p < 4; p++)
        out[z * sOut + (long)(n0 + ty + 8 * p) * Kd + k0 + tx] = __float2bfloat16(t[tx][ty + 8 * p]);
}

// ---------------- concat q/k/v biases ----------------
__global__ __launch_bounds__(256) void biascat(
    const float* __restrict__ qb, const float* __restrict__ kb,
    const float* __restrict__ vb, float* __restrict__ out)
{
    int i = blockIdx.x * 256 + threadIdx.x;
    if (i >= 4 * 1536) return;
    int l = i / 1536, j = i - l * 1536;
    float v = (j < 512) ? qb[l * 512 + j] : (j < 1024) ? kb[l * 512 + j - 512] : vb[l * 512 + j - 1024];
    out[i] = v;
}

// ---------------- residual + LayerNorm -> f32 h + bf16 copy into padded hbp ----------------
__global__ __launch_bounds__(256) void ln_kernel(
    float* __restrict__ h, bf16* __restrict__ hbp, const float* __restrict__ r,
    const float* __restrict__ sc, const float* __restrict__ bi)
{
    long base = (long)blockIdx.x * Dm;
    int b = blockIdx.x >> 9;
    long hbase = base + (long)(b + 1) * 1024;   // hbp row = bl + 2*b + 2
    int tid = threadIdx.x;
    float v0 = h[base + tid] + r[base + tid];
    float v1 = h[base + tid + 256] + r[base + tid + 256];
    __shared__ float red[16];
    int lane = tid & 63, wid = tid >> 6;
    float s = v0 + v1;
    for (int off = 32; off; off >>= 1) s += __shfl_down(s, off);
    if (!lane) red[wid] = s;
    __syncthreads();
    float mean = (red[0] + red[1] + red[2] + red[3]) * (1.f / 512.f);
    float d0 = v0 - mean, d1 = v1 - mean;
    float vs = d0 * d0 + d1 * d1;
    for (int off = 32; off; off >>= 1) vs += __shfl_down(vs, off);
    if (!lane) red[4 + wid] = vs;
    __syncthreads();
    float var = (red[4] + red[5] + red[6] + red[7]) * (1.f / 512.f);
    float inv = rsqrtf(var + 1e-5f);
    float o0 = d0 * inv * sc[tid] + bi[tid];
    float o1 = d1 * inv * sc[tid + 256] + bi[tid + 256];
    h[base + tid]         = o0;
    h[base + tid + 256]   = o1;
    hbp[hbase + tid]       = __float2bfloat16(o0);
    hbp[hbase + tid + 256] = __float2bfloat16(o1);
}

// ---------------- v transpose: qkv v-part [pos][d] -> vT [z][d][pos] bf16 ----------------
__global__ __launch_bounds__(256) void vtrans(const bf16* __restrict__ qkv, bf16* __restrict__ vT)
{
    int z = blockIdx.y, b = z >> 3, hh = z & 7;
    int pos0 = blockIdx.x * 64;
    __shared__ bf16 T[64][65];
    int tid = threadIdx.x;
    int d = tid & 63, pr = tid >> 6;
    const bf16* src = qkv + ((long)(b * 512 + pos0)) * 1536 + 1024 + hh * 64;
#pragma unroll
    for (int p = 0; p < 16; p++)
        T[pr + 4 * p][d] = src[(long)(pr + 4 * p) * 1536 + d];
    __syncthreads();
    bf16* dst = vT + (long)z * 32768 + pos0;
    int c = tid & 63, dr = tid >> 6;
#pragma unroll
    for (int p = 0; p < 16; p++)
        dst[(long)(dr + 4 * p) * 512 + c] = T[c][dr + 4 * p];
}

// ---------------- MFMA bf16 GEMM: one wave / 64x64 tile, LDS double-buffer, no barriers ----------
// A: [M][K] bf16 (lda), B: [N][K] bf16 (ldb). z: zb=z/zdiv, zr=z%zdiv.
// flags: 1 = skip tiles with bx>by (triangular), 2 = Kend = min(K, m0+64) (causal A).
// Pipeline: coalesced global_load_lds (width 16) into next LDS buffer, s_waitcnt vmcnt(8)
// waits only the current buffer's 8 loads (single wave -> no __syncthreads needed).
__global__ __launch_bounds__(64) void mm_bt(
    const bf16* __restrict__ A, int lda, long sAo, long sAi,
    const bf16* __restrict__ B, int ldb, long sBo, long sBi,
    float* __restrict__ Cf, bf16* __restrict__ Cb, int ldc, long sCo, long sCi,
    int K, int zdiv, int Nvalid, int flags,
    const float* __restrict__ bias, const float* __restrict__ Res,
    bf16* __restrict__ C2, int relu, float scale)
{
    if ((flags & 1) && blockIdx.x > blockIdx.y) return;
    int z = blockIdx.z;
    int zb = z / zdiv, zr = z - zb * zdiv;
    const bf16* Ap = A + zb * sAo + zr * sAi;
    const bf16* Bp = B + zb * sBo + zr * sBi;
    long cbase = zb * sCo + zr * sCi;
    int m0 = blockIdx.y * 64, n0 = blockIdx.x * 64;
    __shared__ __align__(16) bf16 As[2][2048];   // two 64x32 panels
    __shared__ __align__(16) bf16 Bs[2][2048];
    int lane = threadIdx.x;
    int lr = lane >> 2, lc = (lane & 3) * 8;     // staging: 4 lanes cover 64B of one row
    int fm = lane & 15, fq = lane >> 4;
    const bf16* gA[4]; const bf16* gB[4];
#pragma unroll
    for (int p = 0; p < 4; p++) {
        gA[p] = Ap + (long)(m0 + p * 16 + lr) * lda + lc;
        gB[p] = Bp + (long)(n0 + p * 16 + lr) * ldb + lc;
    }
    int Kend = (flags & 2) ? ((K < m0 + 64) ? K : (m0 + 64)) : K;
    int nIter = Kend >> 5;
    f32x4 acc[4][4] = {};
    // preload buffer 0
#pragma unroll
    for (int p = 0; p < 4; p++) {
        __builtin_amdgcn_global_load_lds((const AS1 void*)gA[p], (AS3 void*)(&As[0][p * 512]), 16, 0, 0);
        __builtin_amdgcn_global_load_lds((const AS1 void*)gB[p], (AS3 void*)(&Bs[0][p * 512]), 16, 0, 0);
    }
    for (int it = 0; it < nIter; ++it) {
        int cur = it & 1;
        if (it + 1 < nIter) {
            int nk = (it + 1) << 5;
#pragma unroll
            for (int p = 0; p < 4; p++) {
                __builtin_amdgcn_global_load_lds((const AS1 void*)(gA[p] + nk), (AS3 void*)(&As[cur ^ 1][p * 512]), 16, 0, 0);
                __builtin_amdgcn_global_load_lds((const AS1 void*)(gB[p] + nk), (AS3 void*)(&Bs[cur ^ 1][p * 512]), 16, 0, 0);
            }
            __asm__ __volatile__("s_waitcnt vmcnt(8)" ::: "memory");
        } else {
            __asm__ __volatile__("s_waitcnt vmcnt(0)" ::: "memory");
        }
        bf16x8 af[4], bfr[4];
#pragma unroll
        for (int t = 0; t < 4; t++) {
            af[t]  = *(const bf16x8*)(&As[cur][(t * 16 + fm) * 32 + fq * 8]);
            bfr[t] = *(const bf16x8*)(&Bs[cur][(t * 16 + fm) * 32 + fq * 8]);
        }
#pragma unroll
        for (int i = 0; i < 4; i++)
#pragma unroll
            for (int j = 0; j < 4; j++)
                acc[i][j] = __builtin_amdgcn_mfma_f32_16x16x32_bf16(af[i], bfr[j], acc[i][j], 0, 0, 0);
    }

#pragma unroll
    for (int i = 0; i < 4; i++) {
        int mrow = m0 + i * 16 + fq * 4;
#pragma unroll
        for (int j = 0; j < 4; j++) {
            int n = n0 + j * 16 + fm;
            if (n < Nvalid) {
                float bs = bias ? bias[n] : 0.f;
#pragma unroll
                for (int r = 0; r < 4; r++) {
                    float c = acc[i][j][r] * scale + bs;
                    if (relu) c = fmaxf(c, 0.f);
                    long addr = cbase + (long)(mrow + r) * ldc + n;
                    if (Res) c += Res[addr];
                    if (Cf) Cf[addr] = c;
                    else    Cb[addr] = __float2bfloat16(c);
                    if (C2) C2[addr + (long)(((mrow + r) >> 9) + 1) * 1024] = __float2bfloat16(c);
                }
            }
        }
    }
}

// ---------------- top-k(256) threshold (exact radix select) + softmax; one wave per row ----------
__global__ __launch_bounds__(256) void topk_softmax(float* __restrict__ sc)
{
    int wave = threadIdx.x >> 6, lane = threadIdx.x & 63;
    int row = blockIdx.x * 4 + wave;   // z*512 + q
    int q = row & 511, z = row >> 9;
    float* s = sc + (long)z * 262144 + (long)q * 512;
    __shared__ int hist[4][256];
    int* H = hist[wave];
    float v[8]; unsigned key[8]; bool val[8];
#pragma unroll
    for (int p = 0; p < 8; p++) {
        int c = lane + 64 * p;
        val[p] = (c <= q);
        v[p] = val[p] ? s[c] : NEG;
        unsigned u = __float_as_uint(v[p]);
        key[p] = u ^ (unsigned)(((int)u >> 31) | 0x80000000);
    }
    unsigned prefix = 0u, pmask = 0u; int kneed = 256;
#pragma unroll
    for (int shift = 24; shift >= 0; shift -= 8) {
#pragma unroll
        for (int i = 0; i < 4; i++) H[lane * 4 + i] = 0;
        __syncthreads();
#pragma unroll
        for (int p = 0; p < 8; p++)
            if (val[p] && (key[p] & pmask) == prefix)
                atomicAdd(&H[(key[p] >> shift) & 255], 1);
        __syncthreads();
        int b4 = lane * 4;
        int s0 = H[b4], s1 = H[b4 + 1], s2 = H[b4 + 2], s3 = H[b4 + 3];
        int tot = s0 + s1 + s2 + s3, run = tot;
#pragma unroll
        for (int off = 1; off < 64; off <<= 1) {
            int o = __shfl_down(run, off);
            if (lane + off < 64) run += o;
        }
        int above = run - tot;
        unsigned pack = 0u;
        if (above < kneed && kneed <= above + tot) {
            int c3 = above + s3, c2 = c3 + s2, c1 = c2 + s1;
            int dsel, rem;
            if (kneed <= c3)      { dsel = 3; rem = kneed - above; }
            else if (kneed <= c2) { dsel = 2; rem = kneed - c3; }
            else if (kneed <= c1) { dsel = 1; rem = kneed - c2; }
            else                  { dsel = 0; rem = kneed - c1; }
            pack = ((unsigned)(b4 + dsel) << 10) | (unsigned)rem;
        }
#pragma unroll
        for (int off = 1; off < 64; off <<= 1) pack |= __shfl_xor(pack, off);
        prefix |= (pack >> 10) << shift;
        kneed = (int)(pack & 1023u);
        pmask |= (0xFFu << shift);
        __syncthreads();
    }
    unsigned Tkey = prefix;
    float m = NEG;
#pragma unroll
    for (int p = 0; p < 8; p++) m = fmaxf(m, v[p]);
#pragma unroll
    for (int off = 1; off < 64; off <<= 1) m = fmaxf(m, __shfl_xor(m, off));
    float e[8]; float ssum = 0.f;
#pragma unroll
    for (int p = 0; p < 8; p++) {
        bool kp = val[p] && (key[p] >= Tkey);
        e[p] = kp ? expf(v[p] - m) : 0.f;
        ssum += e[p];
    }
#pragma unroll
    for (int off = 1; off < 64; off <<= 1) ssum += __shfl_xor(ssum, off);
    float inv = 1.f / ssum;
    bf16* sb = (bf16*)s;                  // in-place bf16 probs, row stride 1024 bf16
#pragma unroll
    for (int p = 0; p < 8; p++) sb[lane + 64 * p] = __float2bfloat16(e[p] * inv);
}

extern "C" void kernel_launch(void* const* d_in, const int* in_sizes, int n_in,
                              void* d_out, int out_size, void* d_ws, size_t ws_size,
                              hipStream_t stream)
{
    const float* x         = (const float*)d_in[0];
    const float* tf        = (const float*)d_in[1];
    const float* in_w      = (const float*)d_in[2];
    const float* in_b      = (const float*)d_in[3];
    const float* pos_emb   = (const float*)d_in[4];
    const float* temp_w    = (const float*)d_in[5];
    const float* temp_b    = (const float*)d_in[6];
    const float* pos_scale = (const float*)d_in[7];
    const float* temp_scale= (const float*)d_in[8];
    const float* conv_w    = (const float*)d_in[9];
    const float* conv_b    = (const float*)d_in[10];
    const float* qw        = (const float*)d_in[11];
    const float* qb        = (const float*)d_in[12];
    const float* kw        = (const float*)d_in[13];
    const float* kb        = (const float*)d_in[14];
    const float* vw        = (const float*)d_in[15];
    const float* vb        = (const float*)d_in[16];
    const float* ow        = (const float*)d_in[17];
    const float* ob        = (const float*)d_in[18];
    const float* f1w       = (const float*)d_in[19];
    const float* f1b       = (const float*)d_in[20];
    const float* f2w       = (const float*)d_in[21];
    const float* f2b       = (const float*)d_in[22];
    const float* n1s       = (const float*)d_in[23];
    const float* n1b       = (const float*)d_in[24];
    const float* n2s       = (const float*)d_in[25];
    const float* n2b       = (const float*)d_in[26];

    if (ws_size < (size_t)B_END) return;

    char* wsb = (char*)d_ws;
    float* h    = (float*)(wsb + B_H);
    float* tmp  = (float*)(wsb + B_TMP);
    float* scb  = (float*)(wsb + B_SC);
    float* extras = (float*)(wsb + B_SC);          // reuses scores region before attention
    bf16*  xb   = (bf16*)(wsb + B_HB);
    bf16*  inwT = (bf16*)(wsb + B_HB + 1048576);
    bf16*  hbp  = (bf16*)(wsb + B_HPAD);           // [8][514][512] padded bf16 h
    bf16*  qkv  = (bf16*)(wsb + B_QKV);
    bf16*  vT   = (bf16*)(wsb + B_VT);
    bf16*  ao   = (bf16*)(wsb + B_AO);
    bf16*  mid  = (bf16*)(wsb + B_MID);
    bf16*  wC   = (bf16*)(wsb + B_WC);
    bf16*  wQKV = (bf16*)(wsb + B_WQKV);
    bf16*  wO   = (bf16*)(wsb + B_WO);
    bf16*  wF1  = (bf16*)(wsb + B_WF1);
    bf16*  wF2  = (bf16*)(wsb + B_WF2);
    float* bqkv = (float*)(wsb + B_BIAS);

    // ---- weight prep ----
    convw_bf<<<(4 * 512 * 1536) / 256, 256, 0, stream>>>(conv_w, wC);
    {
        dim3 gw(16, 2, 1);
        wtrans<<<gw, 256, 0, stream>>>(in_w, inwT,         512, 64, 0L, 0L);
        dim3 g(16, 16, 4);
        wtrans<<<g, 256, 0, stream>>>(qw, wQKV,            512, 512, 262144L, 786432L);
        wtrans<<<g, 256, 0, stream>>>(kw, wQKV + 262144,   512, 512, 262144L, 786432L);
        wtrans<<<g, 256, 0, stream>>>(vw, wQKV + 524288,   512, 512, 262144L, 786432L);
        wtrans<<<g, 256, 0, stream>>>(ow, wO,              512, 512, 262144L, 262144L);
        dim3 g1(64, 16, 4);
        wtrans<<<g1, 256, 0, stream>>>(f1w, wF1,          2048, 512, 1048576L, 1048576L);
        dim3 g2(16, 64, 4);
        wtrans<<<g2, 256, 0, stream>>>(f2w, wF2,           512, 2048, 1048576L, 1048576L);
    }
    biascat<<<24, 256, 0, stream>>>(qb, kb, vb, bqkv);
    zpad<<<32, 256, 0, stream>>>(hbp);
    prep_embed<<<4096, 256, 0, stream>>>(x, tf, in_b, pos_emb, temp_w, temp_b,
                                         pos_scale, temp_scale, xb, extras);
    // embed = x @ in_w + extras  -> h (f32) + hbp (bf16, padded)
    {
        dim3 g(8, 64, 1);
        mm_bt<<<g, 64, 0, stream>>>(xb, 64, 0L, 0L,
                                    inwT, 64, 0L, 0L,
                                    h, nullptr, 512, 0L, 0L,
                                    64, 1, 512, 0,
                                    nullptr, extras, hbp, 0, 1.f);
    }

    for (int l = 0; l < El; l++) {
        // causal conv as GEMM over padded hbp window, K = 3*512, z-batched
        {
            dim3 g(8, 8, 8);
            mm_bt<<<g, 64, 0, stream>>>(hbp, 512, 263168L, 0L,
                                        wC + (long)l * 786432, 1536, 0L, 0L,
                                        tmp, nullptr, 512, 262144L, 0L,
                                        1536, 1, 512, 0,
                                        conv_b + (long)l * 512, nullptr, nullptr, 0, 1.f);
        }
        ln_kernel<<<Bsz * Lq, 256, 0, stream>>>(h, hbp, tmp, n1s + (long)l * 512, n1b + (long)l * 512);

        // fused QKV (z-batched over batch): [512,512] @ [512,1536] per b
        {
            dim3 g(24, 8, 8);
            mm_bt<<<g, 64, 0, stream>>>(hbp + 1024, 512, 263168L, 0L,
                                        wQKV + (long)l * 786432, 512, 0L, 0L,
                                        nullptr, qkv, 1536, 786432L, 0L,
                                        512, 1, 1536, 0,
                                        bqkv + (long)l * 1536, nullptr, nullptr, 0, 1.f);
        }

        // scores = 0.125 * q @ k^T (lower-triangle tiles) -> f32 scb
        {
            dim3 g(8, 8, 64);
            mm_bt<<<g, 64, 0, stream>>>(qkv, 1536, 786432L, 64L,
                                        qkv + 512, 1536, 786432L, 64L,
                                        scb, nullptr, 512, 2097152L, 262144L,
                                        64, 8, 512, 1,
                                        nullptr, nullptr, nullptr, 0, 0.125f);
        }
        topk_softmax<<<Bsz * Hh * Lq / 4, 256, 0, stream>>>(scb);
        {
            dim3 gv(8, 64, 1);
            vtrans<<<gv, 256, 0, stream>>>(qkv, vT);
        }
        // attn @ v : causal K limit, Nvalid=64
        {
            dim3 g(1, 8, 64);
            mm_bt<<<g, 64, 0, stream>>>((const bf16*)scb, 1024, 4194304L, 524288L,
                                        vT, 512, 262144L, 32768L,
                                        nullptr, ao, 512, 262144L, 64L,
                                        512, 8, 64, 2,
                                        nullptr, nullptr, nullptr, 0, 1.f);
        }
        // out proj
        {
            dim3 g(8, 64, 1);
            mm_bt<<<g, 64, 0, stream>>>(ao, 512, 0L, 0L,
                                        wO + (long)l * 262144, 512, 0L, 0L,
                                        tmp, nullptr, 512, 0L, 0L,
                                        512, 1, 512, 0,
                                        ob + (long)l * 512, nullptr, nullptr, 0, 1.f);
        }
        ln_kernel<<<Bsz * Lq, 256, 0, stream>>>(h, hbp, tmp, n2s + (long)l * 512, n2b + (long)l * 512);

        // FFN1 (relu) -> bf16 mid, z-batched
        {
            dim3 g(32, 8, 8);
            mm_bt<<<g, 64, 0, stream>>>(hbp + 1024, 512, 263168L, 0L,
                                        wF1 + (long)l * 1048576, 512, 0L, 0L,
                                        nullptr, mid, 2048, 1048576L, 0L,
                                        512, 1, 2048, 0,
                                        f1b + (long)l * 2048, nullptr, nullptr, 1, 1.f);
        }
        // FFN2 + residual -> f32 h + bf16 hbp (padded)
        {
            dim3 g(8, 64, 1);
            mm_bt<<<g, 64, 0, stream>>>(mid, 2048, 0L, 0L,
                                        wF2 + (long)l * 1048576, 2048, 0L, 0L,
                                        h, nullptr, 512, 0L, 0L,
                                        2048, 1, 512, 0,
                                        f2b + (long)l * 512, h, hbp, 0, 1.f);
        }
    }

    hipMemcpyAsync(d_out, h, (size_t)out_size * sizeof(float), hipMemcpyDeviceToDevice, stream);
}